// Round 5
// baseline (947.815 us; speedup 1.0000x reference)
//
#include <hip/hip_runtime.h>
#include <math.h>

#define NENT 128
#define BB 16

__device__ __forceinline__ float sigf(float x) { return 1.0f / (1.0f + __expf(-x)); }

// 4-entity register-blocked 64-dot against a register-resident weight column.
#define GEMV4_BODY(NB, A0, A1, A2, A3)                                        \
    _Pragma("unroll")                                                         \
    for (int i4 = 0; i4 < 16; ++i4) {                                         \
        const float4 e0 = *(const float4*)&s_ee[(NB) + 0][i4 * 4];            \
        const float4 e1 = *(const float4*)&s_ee[(NB) + 1][i4 * 4];            \
        const float4 e2 = *(const float4*)&s_ee[(NB) + 2][i4 * 4];            \
        const float4 e3 = *(const float4*)&s_ee[(NB) + 3][i4 * 4];            \
        A0 = fmaf(e0.x, wr[i4 * 4 + 0], A0); A0 = fmaf(e0.y, wr[i4 * 4 + 1], A0); \
        A0 = fmaf(e0.z, wr[i4 * 4 + 2], A0); A0 = fmaf(e0.w, wr[i4 * 4 + 3], A0); \
        A1 = fmaf(e1.x, wr[i4 * 4 + 0], A1); A1 = fmaf(e1.y, wr[i4 * 4 + 1], A1); \
        A1 = fmaf(e1.z, wr[i4 * 4 + 2], A1); A1 = fmaf(e1.w, wr[i4 * 4 + 3], A1); \
        A2 = fmaf(e2.x, wr[i4 * 4 + 0], A2); A2 = fmaf(e2.y, wr[i4 * 4 + 1], A2); \
        A2 = fmaf(e2.z, wr[i4 * 4 + 2], A2); A2 = fmaf(e2.w, wr[i4 * 4 + 3], A2); \
        A3 = fmaf(e3.x, wr[i4 * 4 + 0], A3); A3 = fmaf(e3.y, wr[i4 * 4 + 1], A3); \
        A3 = fmaf(e3.z, wr[i4 * 4 + 2], A3); A3 = fmaf(e3.w, wr[i4 * 4 + 3], A3); \
    }

// ---------------- Kernel A: encoders + masked MHA -> combined into out[:,12:140)
__global__ __launch_bounds__(256) void ka_attention(
    const float* __restrict__ self_feat,   // (B,24)
    const float* __restrict__ entities,    // (B,128,12)
    const void*  __restrict__ mask_raw,    // (B,128) int32 or uint8
    const float* __restrict__ W_se, const float* __restrict__ b_se,
    const float* __restrict__ W_ee, const float* __restrict__ b_ee,
    const float* __restrict__ W_q,  const float* __restrict__ b_q,
    const float* __restrict__ W_k,  const float* __restrict__ b_k,
    const float* __restrict__ W_v,  const float* __restrict__ b_v,
    float* out)                            // (B,268)
{
    const int b = blockIdx.x;
    const int t = threadIdx.x;
    const int o = t & 63;       // output dim within 64
    const int sub = t >> 6;     // wave id 0..3
    const int h = o >> 4;       // head of this output dim

    __shared__ float s_ee[NENT][64];    // ent_embed, 32 KB
    __shared__ float s_emb[64];
    __shared__ float s_q[64];
    __shared__ float s_attn[4][NENT];   // scores -> attn weights
    __shared__ float s_part[4][64];

    // ---- mask dtype probe (uniform; int32 storage => all first-64 words in {0,1})
    bool mask_is_int = true;
    {
        const unsigned int* mw = (const unsigned int*)mask_raw;
        #pragma unroll
        for (int w0 = 0; w0 < 64; ++w0) mask_is_int = mask_is_int && (mw[w0] <= 1u);
    }

    // ---- self_embed (wave 0)
    if (t < 64) {
        float acc = b_se[o];
        #pragma unroll
        for (int i = 0; i < 24; ++i) acc = fmaf(self_feat[b * 24 + i], W_se[i * 64 + o], acc);
        s_emb[o] = fmaxf(acc, 0.0f);
    }
    __syncthreads();

    // ---- q (wave 0) + entity encoder (all waves)
    if (t < 64) {
        float acc = b_q[o];
        #pragma unroll 8
        for (int i = 0; i < 64; ++i) acc = fmaf(s_emb[i], W_q[i * 64 + o], acc);
        s_q[o] = acc;
    }
    {
        float we[12];
        #pragma unroll
        for (int i = 0; i < 12; ++i) we[i] = W_ee[i * 64 + o];
        const float bee = b_ee[o];
        const float* erow = entities + (size_t)b * (NENT * 12);
        for (int rep = 0; rep < 32; ++rep) {
            const int n = rep * 4 + sub;
            float acc = bee;
            #pragma unroll
            for (int i = 0; i < 12; ++i) acc = fmaf(erow[n * 12 + i], we[i], acc);
            s_ee[n][o] = fmaxf(acc, 0.0f);
        }
    }
    __syncthreads();

    // ---- K pass: k = ee @ W_k + b_k ; scores[h][n] = q.k / 4
    {
        float wr[64];
        #pragma unroll
        for (int i = 0; i < 64; ++i) wr[i] = W_k[i * 64 + o];
        const float bk = b_k[o];
        const float qo = s_q[o];
        for (int ng = 0; ng < 8; ++ng) {
            const int nb = ng * 16 + sub * 4;
            float a0 = bk, a1 = bk, a2 = bk, a3 = bk;
            GEMV4_BODY(nb, a0, a1, a2, a3)
            a0 *= qo; a1 *= qo; a2 *= qo; a3 *= qo;
            #pragma unroll
            for (int d = 1; d < 16; d <<= 1) {
                a0 += __shfl_xor(a0, d); a1 += __shfl_xor(a1, d);
                a2 += __shfl_xor(a2, d); a3 += __shfl_xor(a3, d);
            }
            if ((o & 15) == 0) {
                s_attn[h][nb + 0] = a0 * 0.25f; s_attn[h][nb + 1] = a1 * 0.25f;
                s_attn[h][nb + 2] = a2 * 0.25f; s_attn[h][nb + 3] = a3 * 0.25f;
            }
        }
    }
    __syncthreads();

    // ---- masked softmax: wave `sub` handles head `sub` (128 scores, 2/lane)
    {
        const int lane = o;
        float sc0 = s_attn[sub][lane];
        float sc1 = s_attn[sub][lane + 64];
        bool m0, m1;
        if (mask_is_int) {
            const int* mi = (const int*)mask_raw;
            m0 = mi[(size_t)b * NENT + lane]      != 0;
            m1 = mi[(size_t)b * NENT + lane + 64] != 0;
        } else {
            const unsigned char* mb = (const unsigned char*)mask_raw;
            m0 = mb[(size_t)b * NENT + lane]      != 0;
            m1 = mb[(size_t)b * NENT + lane + 64] != 0;
        }
        sc0 = m0 ? sc0 : -1e30f;
        sc1 = m1 ? sc1 : -1e30f;
        float mx = fmaxf(sc0, sc1);
        #pragma unroll
        for (int d = 1; d < 64; d <<= 1) mx = fmaxf(mx, __shfl_xor(mx, d));
        const float e0 = __expf(sc0 - mx), e1 = __expf(sc1 - mx);
        float sm = e0 + e1;
        #pragma unroll
        for (int d = 1; d < 64; d <<= 1) sm += __shfl_xor(sm, d);
        const float inv = 1.0f / sm;
        s_attn[sub][lane]      = e0 * inv;
        s_attn[sub][lane + 64] = e1 * inv;
    }
    __syncthreads();

    // ---- V pass: v = ee @ W_v + b_v ; attn_out[o] = sum_n attn[h][n] * v[n][o]
    {
        float wr[64];
        #pragma unroll
        for (int i = 0; i < 64; ++i) wr[i] = W_v[i * 64 + o];
        const float bv = b_v[o];
        float acc_o = 0.0f;
        for (int ng = 0; ng < 8; ++ng) {
            const int nb = ng * 16 + sub * 4;
            float a0 = bv, a1 = bv, a2 = bv, a3 = bv;
            GEMV4_BODY(nb, a0, a1, a2, a3)
            acc_o = fmaf(s_attn[h][nb + 0], a0, acc_o);
            acc_o = fmaf(s_attn[h][nb + 1], a1, acc_o);
            acc_o = fmaf(s_attn[h][nb + 2], a2, acc_o);
            acc_o = fmaf(s_attn[h][nb + 3], a3, acc_o);
        }
        s_part[sub][o] = acc_o;
    }
    __syncthreads();

    if (t < 64) {
        const float ao = s_part[0][o] + s_part[1][o] + s_part[2][o] + s_part[3][o];
        out[(size_t)b * 268 + 12 + o] = s_emb[o];   // combined[0:64)  = self_embed
        out[(size_t)b * 268 + 76 + o] = ao;         // combined[64:128)= attn_out
    }
}

// 128x128 GEMV over BB rows staged in LDS; weights from global (L2-resident).
__device__ __forceinline__ void gemv128(const float (*s_in)[128], float (*s_out)[128],
                                        const float* __restrict__ W,
                                        const float* __restrict__ bvec,
                                        int t, bool relu_)
{
    const int oo = t & 127;
    const int rb = (t >> 7) * 8;
    const float bv = bvec[oo];
    float acc[8];
    #pragma unroll
    for (int r = 0; r < 8; ++r) acc[r] = bv;
    #pragma unroll 4
    for (int i = 0; i < 128; ++i) {
        const float w = W[i * 128 + oo];
        #pragma unroll
        for (int r = 0; r < 8; ++r) acc[r] = fmaf(s_in[rb + r][i], w, acc[r]);
    }
    #pragma unroll
    for (int r = 0; r < 8; ++r) s_out[rb + r][oo] = relu_ ? fmaxf(acc[r], 0.0f) : acc[r];
}

// ---------------- Kernel B: MLP + LSTM + actor heads (16 rows per block)
__global__ __launch_bounds__(256) void kb_lstm_heads(
    const float* __restrict__ hx, const float* __restrict__ cx,
    const float* __restrict__ W_p1, const float* __restrict__ b_p1,
    const float* __restrict__ W_p2, const float* __restrict__ b_p2,
    const float* __restrict__ W_ih, const float* __restrict__ b_ih,
    const float* __restrict__ W_hh, const float* __restrict__ b_hh,
    const float* __restrict__ W_a,  const float* __restrict__ b_a,
    const float* __restrict__ W_mx, const float* __restrict__ b_mx,
    const float* __restrict__ W_my, const float* __restrict__ b_my,
    const float* __restrict__ W_fi, const float* __restrict__ b_fi,
    const float* __restrict__ W_he, const float* __restrict__ b_he,
    const float* __restrict__ W_ra, const float* __restrict__ b_ra,
    const float* __restrict__ W_rb, const float* __restrict__ b_rb,
    float* out)   // aliases the combined staging area — no __restrict__
{
    const int t = threadIdx.x;
    const int r0 = blockIdx.x * BB;

    __shared__ float s_x[BB][128];   // combined -> reactive -> h
    __shared__ float s_y[BB][128];   // r1 -> features
    __shared__ float s_hx[BB][128];
    __shared__ float s_g[BB][512];   // gates

    // stage combined (written by kernel A into out[:,12:140)) and hx
    for (int idx = t; idx < BB * 128; idx += 256) {
        const int r = idx >> 7, j = idx & 127;
        s_x[r][j]  = out[(size_t)(r0 + r) * 268 + 12 + j];
        s_hx[r][j] = hx[(size_t)(r0 + r) * 128 + j];
    }
    __syncthreads();

    gemv128(s_x, s_y, W_p1, b_p1, t, true);    // r1
    __syncthreads();
    gemv128(s_y, s_x, W_p2, b_p2, t, true);    // reactive
    __syncthreads();

    // ---- LSTM gates: thread t owns output cols t and t+256 across all 16 rows
    {
        float acc1[16], acc2[16];
        const float bs1 = b_ih[t] + b_hh[t];
        const float bs2 = b_ih[t + 256] + b_hh[t + 256];
        #pragma unroll
        for (int r = 0; r < 16; ++r) { acc1[r] = bs1; acc2[r] = bs2; }
        #pragma unroll 4
        for (int i = 0; i < 128; ++i) {
            const float w1 = W_ih[i * 512 + t];
            const float w2 = W_ih[i * 512 + t + 256];
            #pragma unroll
            for (int r = 0; r < 16; ++r) {
                const float x = s_x[r][i];
                acc1[r] = fmaf(x, w1, acc1[r]);
                acc2[r] = fmaf(x, w2, acc2[r]);
            }
        }
        #pragma unroll 4
        for (int i = 0; i < 128; ++i) {
            const float w1 = W_hh[i * 512 + t];
            const float w2 = W_hh[i * 512 + t + 256];
            #pragma unroll
            for (int r = 0; r < 16; ++r) {
                const float x = s_hx[r][i];
                acc1[r] = fmaf(x, w1, acc1[r]);
                acc2[r] = fmaf(x, w2, acc2[r]);
            }
        }
        #pragma unroll
        for (int r = 0; r < 16; ++r) { s_g[r][t] = acc1[r]; s_g[r][t + 256] = acc2[r]; }
    }
    __syncthreads();

    // ---- LSTM elementwise (gate order i,f,g,o); write hx_new/cx_new; features in s_y
    for (int idx = t; idx < BB * 128; idx += 256) {
        const int r = idx >> 7, j = idx & 127;
        const float ig = s_g[r][j];
        const float fg = s_g[r][j + 128];
        const float gg = s_g[r][j + 256];
        const float og = s_g[r][j + 384];
        const float c_old = cx[(size_t)(r0 + r) * 128 + j];
        const float c_new = sigf(fg) * c_old + sigf(ig) * tanhf(gg);
        const float h_new = sigf(og) * tanhf(c_new);
        out[(size_t)(r0 + r) * 268 + 12 + j]  = h_new;
        out[(size_t)(r0 + r) * 268 + 140 + j] = c_new;
        s_y[r][j] = s_x[r][j] + h_new;   // features = reactive + hx_new
    }
    __syncthreads();

    gemv128(s_y, s_x, W_a, b_a, t, true);      // h
    __syncthreads();

    // ---- small heads: 12 scalar outputs per row
    if (t < BB * 12) {
        const int r = t / 12, w = t % 12;
        const float* Wm; const float* bm; int nc, c, off;
        if (w < 3)       { Wm = W_mx; bm = b_mx; nc = 3; c = w;     off = w;  }
        else if (w < 6)  { Wm = W_my; bm = b_my; nc = 3; c = w - 3; off = w;  }
        else if (w < 8)  { Wm = W_fi; bm = b_fi; nc = 2; c = w - 6; off = w;  }
        else if (w < 10) { Wm = W_he; bm = b_he; nc = 2; c = w - 8; off = w;  }
        else if (w == 10){ Wm = W_ra; bm = b_ra; nc = 1; c = 0;     off = 10; }
        else             { Wm = W_rb; bm = b_rb; nc = 1; c = 0;     off = 11; }
        float acc = bm[c];
        for (int i = 0; i < 128; ++i) acc = fmaf(s_x[r][i], Wm[i * nc + c], acc);
        if (w >= 10) acc = fmaxf(acc, 0.0f) + log1pf(__expf(-fabsf(acc))) + 1.0f;
        out[(size_t)(r0 + r) * 268 + off] = acc;
    }
}

extern "C" void kernel_launch(void* const* d_in, const int* in_sizes, int n_in,
                              void* d_out, int out_size, void* d_ws, size_t ws_size,
                              hipStream_t stream) {
    (void)n_in; (void)out_size; (void)d_ws; (void)ws_size;
    const float* self_feat = (const float*)d_in[0];
    const float* entities  = (const float*)d_in[1];
    const void*  mask      = d_in[2];
    const float* hx  = (const float*)d_in[3];
    const float* cx  = (const float*)d_in[4];
    const float* W_se = (const float*)d_in[5],  *b_se = (const float*)d_in[6];
    const float* W_ee = (const float*)d_in[7],  *b_ee = (const float*)d_in[8];
    const float* W_q  = (const float*)d_in[9],  *b_q  = (const float*)d_in[10];
    const float* W_k  = (const float*)d_in[11], *b_k  = (const float*)d_in[12];
    const float* W_v  = (const float*)d_in[13], *b_v  = (const float*)d_in[14];
    const float* W_p1 = (const float*)d_in[15], *b_p1 = (const float*)d_in[16];
    const float* W_p2 = (const float*)d_in[17], *b_p2 = (const float*)d_in[18];
    const float* W_ih = (const float*)d_in[19], *b_ih = (const float*)d_in[20];
    const float* W_hh = (const float*)d_in[21], *b_hh = (const float*)d_in[22];
    const float* W_a  = (const float*)d_in[23], *b_a  = (const float*)d_in[24];
    const float* W_mx = (const float*)d_in[25], *b_mx = (const float*)d_in[26];
    const float* W_my = (const float*)d_in[27], *b_my = (const float*)d_in[28];
    const float* W_fi = (const float*)d_in[29], *b_fi = (const float*)d_in[30];
    const float* W_he = (const float*)d_in[31], *b_he = (const float*)d_in[32];
    const float* W_ra = (const float*)d_in[33], *b_ra = (const float*)d_in[34];
    const float* W_rb = (const float*)d_in[35], *b_rb = (const float*)d_in[36];
    float* out = (float*)d_out;

    const int B = in_sizes[0] / 24;   // 8192

    ka_attention<<<B, 256, 0, stream>>>(self_feat, entities, mask,
        W_se, b_se, W_ee, b_ee, W_q, b_q, W_k, b_k, W_v, b_v, out);
    kb_lstm_heads<<<B / BB, 256, 0, stream>>>(hx, cx,
        W_p1, b_p1, W_p2, b_p2, W_ih, b_ih, W_hh, b_hh, W_a, b_a,
        W_mx, b_mx, W_my, b_my, W_fi, b_fi, W_he, b_he, W_ra, b_ra, W_rb, b_rb, out);
}

// Round 6
// 383.730 us; speedup vs baseline: 2.4700x; 2.4700x over previous
//
#include <hip/hip_runtime.h>
#include <math.h>

#define BB 16

__device__ __forceinline__ float sigf(float x) { return 1.0f / (1.0f + __expf(-x)); }

// ---------------- Kernel A v2: algebraically-reduced attention.
// Per batch row: score[h][n] = ee[n]·qkh[h] + qb[h]; ctx[h] = sum_n attn*ee[n];
// attn_out = W_v^T ctx (+ b_v). Flash-style online softmax over 4 tiles of 32
// entities; one wave per row, 2 rows per 128-thread block.
__global__ __launch_bounds__(128) void ka_attention_v2(
    const float* __restrict__ self_feat,   // (B,24)
    const float* __restrict__ entities,    // (B,128,12)
    const void*  __restrict__ mask_raw,    // (B,128) int32 or uint8
    const float* __restrict__ W_se, const float* __restrict__ b_se,
    const float* __restrict__ W_ee, const float* __restrict__ b_ee,
    const float* __restrict__ W_q,  const float* __restrict__ b_q,
    const float* __restrict__ W_k,  const float* __restrict__ b_k,
    const float* __restrict__ W_v,  const float* __restrict__ b_v,
    float* out)                            // (B,268)
{
    const int t = threadIdx.x;
    const int w = t >> 6;     // wave = row within block
    const int l = t & 63;
    const int b = blockIdx.x * 2 + w;

    // all LDS regions are wave-private -> no __syncthreads anywhere
    __shared__ float s_ent[2][1536];                    // 12 KB: staged entity rows
    __shared__ float s_eet[2][2048];                    // 16 KB: swizzled ee tile (32x64)
    __shared__ float s_emb[2][64];
    __shared__ __align__(16) float s_qk[2][64][4];      // qkh[i][h]
    __shared__ __align__(16) float s_p[2][32][4];       // tile attn weights (unnorm)
    __shared__ __align__(16) float s_ctx[2][64][4];
    __shared__ __align__(16) float s_qb[2][4];

    // ---- mask dtype probe (uniform)
    bool mask_is_int = true;
    {
        const unsigned int* mw = (const unsigned int*)mask_raw;
        #pragma unroll
        for (int w0 = 0; w0 < 64; ++w0) mask_is_int = mask_is_int && (mw[w0] <= 1u);
    }

    // ---- stage this row's entities (1536 floats, coalesced float4)
    {
        const float4* ef = (const float4*)(entities + (size_t)b * 1536);
        float4* sf4 = (float4*)s_ent[w];
        #pragma unroll
        for (int k = 0; k < 6; ++k) sf4[l + 64 * k] = ef[l + 64 * k];
    }

    // ---- self_embed (lane = output dim)
    float emb = b_se[l];
    #pragma unroll
    for (int i = 0; i < 24; ++i) emb = fmaf(self_feat[b * 24 + i], W_se[i * 64 + l], emb);
    emb = fmaxf(emb, 0.0f);
    s_emb[w][l] = emb;

    // ---- q[l] = emb @ W_q + b_q
    float q = b_q[l];
    #pragma unroll 8
    for (int i = 0; i < 64; ++i) q = fmaf(s_emb[w][i], W_q[i * 64 + l], q);

    // ---- qb[h] = sum_{d in head h} q[d] * b_k[d]
    {
        float v = q * b_k[l];
        v += __shfl_xor(v, 1); v += __shfl_xor(v, 2);
        v += __shfl_xor(v, 4); v += __shfl_xor(v, 8);
        if ((l & 15) == 0) s_qb[w][l >> 4] = v;
    }

    // ---- qkh[h][i] = sum_{d in head h} W_k[i][d] * q[d]   (lane = d, reduce per head)
    #pragma unroll 4
    for (int i = 0; i < 64; ++i) {
        float v = W_k[i * 64 + l] * q;
        v += __shfl_xor(v, 1); v += __shfl_xor(v, 2);
        v += __shfl_xor(v, 4); v += __shfl_xor(v, 8);
        if ((l & 15) == 0) s_qk[w][i][l >> 4] = v;
    }

    // ---- encoder weights, per-lane column of W_ee
    float wee[12];
    #pragma unroll
    for (int i = 0; i < 12; ++i) wee[i] = W_ee[i * 64 + l];
    const float bee = b_ee[l];

    const float4 qbv = *(const float4*)s_qb[w];

    // online softmax state (replicated across all lanes) + ctx accumulators (lane = i)
    float m0 = -1e30f, m1 = -1e30f, m2 = -1e30f, m3 = -1e30f;
    float l0 = 0.f, l1 = 0.f, l2 = 0.f, l3 = 0.f;
    float c0 = 0.f, c1 = 0.f, c2 = 0.f, c3 = 0.f;
    const int n_l = l & 31, ihalf = l >> 5;

    for (int tl = 0; tl < 4; ++tl) {
        // -- encode 32 entities: ee in registers (lane = o) + swizzled LDS copy for transpose
        float eev[32];
        #pragma unroll
        for (int j = 0; j < 32; ++j) {
            const float* en = s_ent[w] + (tl * 32 + j) * 12;   // uniform, 16B-aligned
            const float4 e0 = *(const float4*)(en);
            const float4 e1 = *(const float4*)(en + 4);
            const float4 e2 = *(const float4*)(en + 8);
            float a = bee;
            a = fmaf(e0.x, wee[0], a);  a = fmaf(e0.y, wee[1], a);
            a = fmaf(e0.z, wee[2], a);  a = fmaf(e0.w, wee[3], a);
            a = fmaf(e1.x, wee[4], a);  a = fmaf(e1.y, wee[5], a);
            a = fmaf(e1.z, wee[6], a);  a = fmaf(e1.w, wee[7], a);
            a = fmaf(e2.x, wee[8], a);  a = fmaf(e2.y, wee[9], a);
            a = fmaf(e2.z, wee[10], a); a = fmaf(e2.w, wee[11], a);
            a = fmaxf(a, 0.0f);
            eev[j] = a;
            s_eet[w][j * 64 + (l ^ j)] = a;    // XOR swizzle: conflict-free write & read
        }

        // -- scores: lane n (dup in halves), split i over halves, combine with shfl(32)
        float sc0 = 0.f, sc1 = 0.f, sc2 = 0.f, sc3 = 0.f;
        #pragma unroll
        for (int ii = 0; ii < 32; ++ii) {
            const int i = ihalf * 32 + ii;
            const float e = s_eet[w][n_l * 64 + (i ^ n_l)];
            const float4 qk = *(const float4*)s_qk[w][i];      // uniform b128
            sc0 = fmaf(e, qk.x, sc0); sc1 = fmaf(e, qk.y, sc1);
            sc2 = fmaf(e, qk.z, sc2); sc3 = fmaf(e, qk.w, sc3);
        }
        sc0 += __shfl_xor(sc0, 32); sc1 += __shfl_xor(sc1, 32);
        sc2 += __shfl_xor(sc2, 32); sc3 += __shfl_xor(sc3, 32);

        // -- mask + scale (score = (q.k)/sqrt(16))
        bool msk;
        {
            const int ng = tl * 32 + n_l;
            if (mask_is_int) msk = ((const int*)mask_raw)[(size_t)b * 128 + ng] != 0;
            else             msk = ((const unsigned char*)mask_raw)[(size_t)b * 128 + ng] != 0;
        }
        sc0 = msk ? (sc0 + qbv.x) * 0.25f : -1e30f;
        sc1 = msk ? (sc1 + qbv.y) * 0.25f : -1e30f;
        sc2 = msk ? (sc2 + qbv.z) * 0.25f : -1e30f;
        sc3 = msk ? (sc3 + qbv.w) * 0.25f : -1e30f;

        // -- tile max per head (32 distinct n; halves are duplicates so 5 levels suffice)
        float t0 = sc0, t1 = sc1, t2 = sc2, t3 = sc3;
        #pragma unroll
        for (int d = 1; d < 32; d <<= 1) {
            t0 = fmaxf(t0, __shfl_xor(t0, d)); t1 = fmaxf(t1, __shfl_xor(t1, d));
            t2 = fmaxf(t2, __shfl_xor(t2, d)); t3 = fmaxf(t3, __shfl_xor(t3, d));
        }
        const float mn0 = fmaxf(m0, t0), mn1 = fmaxf(m1, t1);
        const float mn2 = fmaxf(m2, t2), mn3 = fmaxf(m3, t3);
        const float sl0 = __expf(m0 - mn0), sl1 = __expf(m1 - mn1);
        const float sl2 = __expf(m2 - mn2), sl3 = __expf(m3 - mn3);
        const float p0 = msk ? __expf(sc0 - mn0) : 0.0f;
        const float p1 = msk ? __expf(sc1 - mn1) : 0.0f;
        const float p2 = msk ? __expf(sc2 - mn2) : 0.0f;
        const float p3 = msk ? __expf(sc3 - mn3) : 0.0f;

        float ps0 = p0, ps1 = p1, ps2 = p2, ps3 = p3;
        #pragma unroll
        for (int d = 1; d < 32; d <<= 1) {
            ps0 += __shfl_xor(ps0, d); ps1 += __shfl_xor(ps1, d);
            ps2 += __shfl_xor(ps2, d); ps3 += __shfl_xor(ps3, d);
        }
        l0 = l0 * sl0 + ps0; l1 = l1 * sl1 + ps1;
        l2 = l2 * sl2 + ps2; l3 = l3 * sl3 + ps3;
        m0 = mn0; m1 = mn1; m2 = mn2; m3 = mn3;

        // -- publish tile weights, accumulate ctx (lane = i) from register ee
        if (l < 32) {
            float4 pv; pv.x = p0; pv.y = p1; pv.z = p2; pv.w = p3;
            *(float4*)s_p[w][l] = pv;
        }
        c0 *= sl0; c1 *= sl1; c2 *= sl2; c3 *= sl3;
        #pragma unroll
        for (int j = 0; j < 32; ++j) {
            const float4 pv = *(const float4*)s_p[w][j];       // uniform b128
            c0 = fmaf(pv.x, eev[j], c0);
            c1 = fmaf(pv.y, eev[j], c1);
            c2 = fmaf(pv.z, eev[j], c2);
            c3 = fmaf(pv.w, eev[j], c3);
        }
    }

    // ---- normalize ctx, publish, project with W_v
    const float i0 = l0 > 0.f ? 1.f / l0 : 0.f;
    const float i1 = l1 > 0.f ? 1.f / l1 : 0.f;
    const float i2 = l2 > 0.f ? 1.f / l2 : 0.f;
    const float i3 = l3 > 0.f ? 1.f / l3 : 0.f;
    {
        float4 cv; cv.x = c0 * i0; cv.y = c1 * i1; cv.z = c2 * i2; cv.w = c3 * i3;
        *(float4*)s_ctx[w][l] = cv;
    }
    float ao = b_v[l];
    const int h = l >> 4;
    #pragma unroll 8
    for (int i = 0; i < 64; ++i) ao = fmaf(s_ctx[w][i][h], W_v[i * 64 + l], ao);

    out[(size_t)b * 268 + 12 + l] = emb;   // combined[0:64)
    out[(size_t)b * 268 + 76 + l] = ao;    // combined[64:128)
}

// 128x128 GEMV over BB rows staged in LDS; weights from global (L2-resident).
__device__ __forceinline__ void gemv128(const float (*s_in)[128], float (*s_out)[128],
                                        const float* __restrict__ W,
                                        const float* __restrict__ bvec,
                                        int t, bool relu_)
{
    const int oo = t & 127;
    const int rb = (t >> 7) * 8;
    const float bv = bvec[oo];
    float acc[8];
    #pragma unroll
    for (int r = 0; r < 8; ++r) acc[r] = bv;
    #pragma unroll 4
    for (int i = 0; i < 128; ++i) {
        const float w = W[i * 128 + oo];
        #pragma unroll
        for (int r = 0; r < 8; ++r) acc[r] = fmaf(s_in[rb + r][i], w, acc[r]);
    }
    #pragma unroll
    for (int r = 0; r < 8; ++r) s_out[rb + r][oo] = relu_ ? fmaxf(acc[r], 0.0f) : acc[r];
}

// ---------------- Kernel B: MLP + LSTM + actor heads (16 rows per block)
__global__ __launch_bounds__(256) void kb_lstm_heads(
    const float* __restrict__ hx, const float* __restrict__ cx,
    const float* __restrict__ W_p1, const float* __restrict__ b_p1,
    const float* __restrict__ W_p2, const float* __restrict__ b_p2,
    const float* __restrict__ W_ih, const float* __restrict__ b_ih,
    const float* __restrict__ W_hh, const float* __restrict__ b_hh,
    const float* __restrict__ W_a,  const float* __restrict__ b_a,
    const float* __restrict__ W_mx, const float* __restrict__ b_mx,
    const float* __restrict__ W_my, const float* __restrict__ b_my,
    const float* __restrict__ W_fi, const float* __restrict__ b_fi,
    const float* __restrict__ W_he, const float* __restrict__ b_he,
    const float* __restrict__ W_ra, const float* __restrict__ b_ra,
    const float* __restrict__ W_rb, const float* __restrict__ b_rb,
    float* out)   // aliases the combined staging area — no __restrict__
{
    const int t = threadIdx.x;
    const int r0 = blockIdx.x * BB;

    __shared__ float s_x[BB][128];   // combined -> reactive -> h
    __shared__ float s_y[BB][128];   // r1 -> features
    __shared__ float s_hx[BB][128];
    __shared__ float s_g[BB][512];   // gates

    for (int idx = t; idx < BB * 128; idx += 256) {
        const int r = idx >> 7, j = idx & 127;
        s_x[r][j]  = out[(size_t)(r0 + r) * 268 + 12 + j];
        s_hx[r][j] = hx[(size_t)(r0 + r) * 128 + j];
    }
    __syncthreads();

    gemv128(s_x, s_y, W_p1, b_p1, t, true);    // r1
    __syncthreads();
    gemv128(s_y, s_x, W_p2, b_p2, t, true);    // reactive
    __syncthreads();

    // ---- LSTM gates: thread t owns output cols t and t+256 across all 16 rows
    {
        float acc1[16], acc2[16];
        const float bs1 = b_ih[t] + b_hh[t];
        const float bs2 = b_ih[t + 256] + b_hh[t + 256];
        #pragma unroll
        for (int r = 0; r < 16; ++r) { acc1[r] = bs1; acc2[r] = bs2; }
        #pragma unroll 4
        for (int i = 0; i < 128; ++i) {
            const float w1 = W_ih[i * 512 + t];
            const float w2 = W_ih[i * 512 + t + 256];
            #pragma unroll
            for (int r = 0; r < 16; ++r) {
                const float x = s_x[r][i];
                acc1[r] = fmaf(x, w1, acc1[r]);
                acc2[r] = fmaf(x, w2, acc2[r]);
            }
        }
        #pragma unroll 4
        for (int i = 0; i < 128; ++i) {
            const float w1 = W_hh[i * 512 + t];
            const float w2 = W_hh[i * 512 + t + 256];
            #pragma unroll
            for (int r = 0; r < 16; ++r) {
                const float x = s_hx[r][i];
                acc1[r] = fmaf(x, w1, acc1[r]);
                acc2[r] = fmaf(x, w2, acc2[r]);
            }
        }
        #pragma unroll
        for (int r = 0; r < 16; ++r) { s_g[r][t] = acc1[r]; s_g[r][t + 256] = acc2[r]; }
    }
    __syncthreads();

    // ---- LSTM elementwise (gate order i,f,g,o)
    for (int idx = t; idx < BB * 128; idx += 256) {
        const int r = idx >> 7, j = idx & 127;
        const float ig = s_g[r][j];
        const float fg = s_g[r][j + 128];
        const float gg = s_g[r][j + 256];
        const float og = s_g[r][j + 384];
        const float c_old = cx[(size_t)(r0 + r) * 128 + j];
        const float c_new = sigf(fg) * c_old + sigf(ig) * tanhf(gg);
        const float h_new = sigf(og) * tanhf(c_new);
        out[(size_t)(r0 + r) * 268 + 12 + j]  = h_new;
        out[(size_t)(r0 + r) * 268 + 140 + j] = c_new;
        s_y[r][j] = s_x[r][j] + h_new;   // features = reactive + hx_new
    }
    __syncthreads();

    gemv128(s_y, s_x, W_a, b_a, t, true);      // h
    __syncthreads();

    // ---- small heads: 12 scalar outputs per row
    if (t < BB * 12) {
        const int r = t / 12, w = t % 12;
        const float* Wm; const float* bm; int nc, c, off;
        if (w < 3)       { Wm = W_mx; bm = b_mx; nc = 3; c = w;     off = w;  }
        else if (w < 6)  { Wm = W_my; bm = b_my; nc = 3; c = w - 3; off = w;  }
        else if (w < 8)  { Wm = W_fi; bm = b_fi; nc = 2; c = w - 6; off = w;  }
        else if (w < 10) { Wm = W_he; bm = b_he; nc = 2; c = w - 8; off = w;  }
        else if (w == 10){ Wm = W_ra; bm = b_ra; nc = 1; c = 0;     off = 10; }
        else             { Wm = W_rb; bm = b_rb; nc = 1; c = 0;     off = 11; }
        float acc = bm[c];
        for (int i = 0; i < 128; ++i) acc = fmaf(s_x[r][i], Wm[i * nc + c], acc);
        if (w >= 10) acc = fmaxf(acc, 0.0f) + log1pf(__expf(-fabsf(acc))) + 1.0f;
        out[(size_t)(r0 + r) * 268 + off] = acc;
    }
}

extern "C" void kernel_launch(void* const* d_in, const int* in_sizes, int n_in,
                              void* d_out, int out_size, void* d_ws, size_t ws_size,
                              hipStream_t stream) {
    (void)n_in; (void)out_size; (void)d_ws; (void)ws_size;
    const float* self_feat = (const float*)d_in[0];
    const float* entities  = (const float*)d_in[1];
    const void*  mask      = d_in[2];
    const float* hx  = (const float*)d_in[3];
    const float* cx  = (const float*)d_in[4];
    const float* W_se = (const float*)d_in[5],  *b_se = (const float*)d_in[6];
    const float* W_ee = (const float*)d_in[7],  *b_ee = (const float*)d_in[8];
    const float* W_q  = (const float*)d_in[9],  *b_q  = (const float*)d_in[10];
    const float* W_k  = (const float*)d_in[11], *b_k  = (const float*)d_in[12];
    const float* W_v  = (const float*)d_in[13], *b_v  = (const float*)d_in[14];
    const float* W_p1 = (const float*)d_in[15], *b_p1 = (const float*)d_in[16];
    const float* W_p2 = (const float*)d_in[17], *b_p2 = (const float*)d_in[18];
    const float* W_ih = (const float*)d_in[19], *b_ih = (const float*)d_in[20];
    const float* W_hh = (const float*)d_in[21], *b_hh = (const float*)d_in[22];
    const float* W_a  = (const float*)d_in[23], *b_a  = (const float*)d_in[24];
    const float* W_mx = (const float*)d_in[25], *b_mx = (const float*)d_in[26];
    const float* W_my = (const float*)d_in[27], *b_my = (const float*)d_in[28];
    const float* W_fi = (const float*)d_in[29], *b_fi = (const float*)d_in[30];
    const float* W_he = (const float*)d_in[31], *b_he = (const float*)d_in[32];
    const float* W_ra = (const float*)d_in[33], *b_ra = (const float*)d_in[34];
    const float* W_rb = (const float*)d_in[35], *b_rb = (const float*)d_in[36];
    float* out = (float*)d_out;

    const int B = in_sizes[0] / 24;   // 8192

    ka_attention_v2<<<B / 2, 128, 0, stream>>>(self_feat, entities, mask,
        W_se, b_se, W_ee, b_ee, W_q, b_q, W_k, b_k, W_v, b_v, out);
    kb_lstm_heads<<<B / BB, 256, 0, stream>>>(hx, cx,
        W_p1, b_p1, W_p2, b_p2, W_ih, b_ih, W_hh, b_hh, W_a, b_a,
        W_mx, b_mx, W_my, b_my, W_fi, b_fi, W_he, b_he, W_ra, b_ra, W_rb, b_rb, out);
}

// Round 7
// 240.203 us; speedup vs baseline: 3.9459x; 1.5975x over previous
//
#include <hip/hip_runtime.h>
#include <math.h>

#define BB 16

typedef __attribute__((ext_vector_type(8))) unsigned short ushort8;

__device__ __forceinline__ float sigf(float x) { return 1.0f / (1.0f + __expf(-x)); }

__device__ __forceinline__ unsigned short f2bf(float f) {
    unsigned int u = __float_as_uint(f);
    u += 0x7FFFu + ((u >> 16) & 1u);
    return (unsigned short)(u >> 16);
}
__device__ __forceinline__ float bf2f(unsigned short s) {
    return __uint_as_float(((unsigned int)s) << 16);
}

// ---------------- Kernel A v3: one row per 256-thread block (4 waves).
// Reduced attention (score = ee·(W_k^T q per head) + q·b_k; ctx = sum p*ee;
// ao = W_v^T ctx). Two-pass softmax; 4 entity tiles processed by 4 waves in
// parallel. Transpose tile in bf16 with high-bit XOR swizzle -> b128 reads.
__global__ __launch_bounds__(256) void ka_attention_v3(
    const float* __restrict__ self_feat,   // (B,24)
    const float* __restrict__ entities,    // (B,128,12)
    const void*  __restrict__ mask_raw,    // (B,128) int32 or uint8
    const float* __restrict__ W_se, const float* __restrict__ b_se,
    const float* __restrict__ W_ee, const float* __restrict__ b_ee,
    const float* __restrict__ W_q,  const float* __restrict__ b_q,
    const float* __restrict__ W_k,  const float* __restrict__ b_k,
    const float* __restrict__ W_v,  const float* __restrict__ b_v,
    float* out)                            // (B,268)
{
    const int t = threadIdx.x;
    const int l = t & 63;
    const int w = __builtin_amdgcn_readfirstlane(t >> 6);   // wave id, provably uniform
    const int b = blockIdx.x;

    __shared__ unsigned short s_eet[4][2048];              // 16 KB: per-wave bf16 32x64 tiles
    __shared__ __align__(16) float s_p[128 * 4];           // scores -> normalized attn [n][h]
    __shared__ __align__(16) float s_qk[64 * 4];           // qkh [i][h]
    __shared__ float s_qp[4 * 64];                         // q partials
    __shared__ __align__(16) float s_ctxp[4 * 64 * 4];     // ctx partials [wave][i][h]
    __shared__ float s_ctx[64 * 4];                        // ctx [i][h]
    __shared__ float s_aop[4 * 64];                        // attn_out partials
    __shared__ float s_emb[64];
    __shared__ __align__(16) float s_qb[4];

    // ---- mask dtype probe (uniform scalar loads)
    bool mask_is_int = true;
    {
        const unsigned int* mw = (const unsigned int*)mask_raw;
        #pragma unroll
        for (int w0 = 0; w0 < 64; ++w0) mask_is_int = mask_is_int && (mw[w0] <= 1u);
    }

    // ---- P0: self_embed (wave 0 only; lane = dim)
    float emb = 0.0f;
    if (w == 0) {
        emb = b_se[l];
        #pragma unroll
        for (int i = 0; i < 24; ++i) emb = fmaf(self_feat[b * 24 + i], W_se[i * 64 + l], emb);
        emb = fmaxf(emb, 0.0f);
        s_emb[l] = emb;
    }
    __syncthreads();

    // ---- P1: q partials, wave w covers i in [16w, 16w+16)
    {
        float qp = 0.0f;
        #pragma unroll
        for (int ii = 0; ii < 16; ++ii) {
            const int i = w * 16 + ii;
            qp = fmaf(s_emb[i], W_q[i * 64 + l], qp);
        }
        s_qp[w * 64 + l] = qp;
    }
    __syncthreads();

    // ---- P2: assemble q (every wave), qb (wave 0), qkh (cooperative: i=l, h=w)
    {
        const float q = b_q[l] + s_qp[l] + s_qp[64 + l] + s_qp[128 + l] + s_qp[192 + l];
        if (w == 0) {
            float v = q * b_k[l];
            v += __shfl_xor(v, 1); v += __shfl_xor(v, 2);
            v += __shfl_xor(v, 4); v += __shfl_xor(v, 8);
            if ((l & 15) == 0) s_qb[l >> 4] = v;
        }
        const float* wkrow = W_k + l * 64 + w * 16;        // one 64B line per lane
        const float4 k0 = *(const float4*)(wkrow);
        const float4 k1 = *(const float4*)(wkrow + 4);
        const float4 k2 = *(const float4*)(wkrow + 8);
        const float4 k3 = *(const float4*)(wkrow + 12);
        float acc = 0.0f;
        acc = fmaf(k0.x, __shfl(q, w * 16 + 0),  acc);
        acc = fmaf(k0.y, __shfl(q, w * 16 + 1),  acc);
        acc = fmaf(k0.z, __shfl(q, w * 16 + 2),  acc);
        acc = fmaf(k0.w, __shfl(q, w * 16 + 3),  acc);
        acc = fmaf(k1.x, __shfl(q, w * 16 + 4),  acc);
        acc = fmaf(k1.y, __shfl(q, w * 16 + 5),  acc);
        acc = fmaf(k1.z, __shfl(q, w * 16 + 6),  acc);
        acc = fmaf(k1.w, __shfl(q, w * 16 + 7),  acc);
        acc = fmaf(k2.x, __shfl(q, w * 16 + 8),  acc);
        acc = fmaf(k2.y, __shfl(q, w * 16 + 9),  acc);
        acc = fmaf(k2.z, __shfl(q, w * 16 + 10), acc);
        acc = fmaf(k2.w, __shfl(q, w * 16 + 11), acc);
        acc = fmaf(k3.x, __shfl(q, w * 16 + 12), acc);
        acc = fmaf(k3.y, __shfl(q, w * 16 + 13), acc);
        acc = fmaf(k3.z, __shfl(q, w * 16 + 14), acc);
        acc = fmaf(k3.w, __shfl(q, w * 16 + 15), acc);
        s_qk[l * 4 + w] = acc;
    }
    __syncthreads();

    // ---- P3: wave w encodes its 32 entities (lane = dim) + computes their scores
    float eev[32];
    {
        float wee[12];
        #pragma unroll
        for (int i = 0; i < 12; ++i) wee[i] = W_ee[i * 64 + l];
        const float bee = b_ee[l];
        const float* erow = entities + (size_t)b * 1536 + w * 384;   // wave-uniform base
        #pragma unroll 8
        for (int j = 0; j < 32; ++j) {
            const float4 e0 = *(const float4*)(erow + j * 12);
            const float4 e1 = *(const float4*)(erow + j * 12 + 4);
            const float4 e2 = *(const float4*)(erow + j * 12 + 8);
            float a = bee;
            a = fmaf(e0.x, wee[0], a);  a = fmaf(e0.y, wee[1], a);
            a = fmaf(e0.z, wee[2], a);  a = fmaf(e0.w, wee[3], a);
            a = fmaf(e1.x, wee[4], a);  a = fmaf(e1.y, wee[5], a);
            a = fmaf(e1.z, wee[6], a);  a = fmaf(e1.w, wee[7], a);
            a = fmaf(e2.x, wee[8], a);  a = fmaf(e2.y, wee[9], a);
            a = fmaf(e2.z, wee[10], a); a = fmaf(e2.w, wee[11], a);
            a = fmaxf(a, 0.0f);
            eev[j] = a;
            // high-bit XOR swizzle: low 3 bits untouched -> b128-readable rows
            s_eet[w][j * 64 + (l ^ (j & 56))] = f2bf(a);
        }
        // scores for this wave's 32 entities: lane n = l&31, i split across halves
        const int n_l = l & 31, ihalf = l >> 5;
        float sc0 = 0.f, sc1 = 0.f, sc2 = 0.f, sc3 = 0.f;
        #pragma unroll
        for (int blk = 0; blk < 4; ++blk) {
            const int i8 = ihalf * 32 + blk * 8;
            const ushort8 ev = *(const ushort8*)&s_eet[w][n_l * 64 + (i8 ^ (n_l & 56))];
            #pragma unroll
            for (int k = 0; k < 8; ++k) {
                const float e = bf2f(ev[k]);
                const float4 qk = *(const float4*)&s_qk[(i8 + k) * 4];   // uniform b128
                sc0 = fmaf(e, qk.x, sc0); sc1 = fmaf(e, qk.y, sc1);
                sc2 = fmaf(e, qk.z, sc2); sc3 = fmaf(e, qk.w, sc3);
            }
        }
        sc0 += __shfl_xor(sc0, 32); sc1 += __shfl_xor(sc1, 32);
        sc2 += __shfl_xor(sc2, 32); sc3 += __shfl_xor(sc3, 32);

        bool msk;
        {
            const int ng = w * 32 + n_l;
            if (mask_is_int) msk = ((const int*)mask_raw)[(size_t)b * 128 + ng] != 0;
            else             msk = ((const unsigned char*)mask_raw)[(size_t)b * 128 + ng] != 0;
        }
        const float4 qbv = *(const float4*)s_qb;
        sc0 = msk ? (sc0 + qbv.x) * 0.25f : -1e30f;
        sc1 = msk ? (sc1 + qbv.y) * 0.25f : -1e30f;
        sc2 = msk ? (sc2 + qbv.z) * 0.25f : -1e30f;
        sc3 = msk ? (sc3 + qbv.w) * 0.25f : -1e30f;
        if (l < 32) {
            float4 s4; s4.x = sc0; s4.y = sc1; s4.z = sc2; s4.w = sc3;
            *(float4*)&s_p[(w * 32 + n_l) * 4] = s4;
        }
    }
    __syncthreads();

    // ---- P4: softmax, wave w handles head w over 128 entities (2 per lane)
    {
        float sc0 = s_p[l * 4 + w];
        float sc1 = s_p[(l + 64) * 4 + w];
        float mx = fmaxf(sc0, sc1);
        #pragma unroll
        for (int d = 1; d < 64; d <<= 1) mx = fmaxf(mx, __shfl_xor(mx, d));
        const float e0 = __expf(sc0 - mx), e1 = __expf(sc1 - mx);
        float sm = e0 + e1;
        #pragma unroll
        for (int d = 1; d < 64; d <<= 1) sm += __shfl_xor(sm, d);
        const float inv = 1.0f / sm;
        s_p[l * 4 + w]        = e0 * inv;
        s_p[(l + 64) * 4 + w] = e1 * inv;
    }
    __syncthreads();

    // ---- P5: ctx partials from register ee (lane = dim i), wave's 32 entities
    {
        float c0 = 0.f, c1 = 0.f, c2 = 0.f, c3 = 0.f;
        #pragma unroll
        for (int j = 0; j < 32; ++j) {
            const float4 pv = *(const float4*)&s_p[(w * 32 + j) * 4];    // uniform b128
            c0 = fmaf(pv.x, eev[j], c0);
            c1 = fmaf(pv.y, eev[j], c1);
            c2 = fmaf(pv.z, eev[j], c2);
            c3 = fmaf(pv.w, eev[j], c3);
        }
        float4 cv; cv.x = c0; cv.y = c1; cv.z = c2; cv.w = c3;
        *(float4*)&s_ctxp[(w * 64 + l) * 4] = cv;
    }
    __syncthreads();

    // ---- P5.5: sum ctx partials: thread (i=l, h=w)
    s_ctx[l * 4 + w] = s_ctxp[(0 * 64 + l) * 4 + w] + s_ctxp[(1 * 64 + l) * 4 + w]
                     + s_ctxp[(2 * 64 + l) * 4 + w] + s_ctxp[(3 * 64 + l) * 4 + w];
    __syncthreads();

    // ---- P6: attn_out partials: wave w covers i in [16w,16w+16); lane = out dim
    {
        const int h = l >> 4;
        float aop = 0.0f;
        #pragma unroll
        for (int ii = 0; ii < 16; ++ii) {
            const int i = w * 16 + ii;
            aop = fmaf(s_ctx[i * 4 + h], W_v[i * 64 + l], aop);
        }
        s_aop[w * 64 + l] = aop;
    }
    __syncthreads();

    // ---- P7: finalize (wave 0)
    if (w == 0) {
        const float ao = b_v[l] + s_aop[l] + s_aop[64 + l] + s_aop[128 + l] + s_aop[192 + l];
        out[(size_t)b * 268 + 12 + l] = emb;   // combined[0:64)
        out[(size_t)b * 268 + 76 + l] = ao;    // combined[64:128)
    }
}

// 128x128 GEMV over BB rows staged in LDS; weights from global (L2-resident).
__device__ __forceinline__ void gemv128(const float (*s_in)[128], float (*s_out)[128],
                                        const float* __restrict__ W,
                                        const float* __restrict__ bvec,
                                        int t, bool relu_)
{
    const int oo = t & 127;
    const int rb = (t >> 7) * 8;
    const float bv = bvec[oo];
    float acc[8];
    #pragma unroll
    for (int r = 0; r < 8; ++r) acc[r] = bv;
    #pragma unroll 4
    for (int i = 0; i < 128; ++i) {
        const float w = W[i * 128 + oo];
        #pragma unroll
        for (int r = 0; r < 8; ++r) acc[r] = fmaf(s_in[rb + r][i], w, acc[r]);
    }
    #pragma unroll
    for (int r = 0; r < 8; ++r) s_out[rb + r][oo] = relu_ ? fmaxf(acc[r], 0.0f) : acc[r];
}

// ---------------- Kernel B: MLP + LSTM + actor heads (16 rows per block)
__global__ __launch_bounds__(256) void kb_lstm_heads(
    const float* __restrict__ hx, const float* __restrict__ cx,
    const float* __restrict__ W_p1, const float* __restrict__ b_p1,
    const float* __restrict__ W_p2, const float* __restrict__ b_p2,
    const float* __restrict__ W_ih, const float* __restrict__ b_ih,
    const float* __restrict__ W_hh, const float* __restrict__ b_hh,
    const float* __restrict__ W_a,  const float* __restrict__ b_a,
    const float* __restrict__ W_mx, const float* __restrict__ b_mx,
    const float* __restrict__ W_my, const float* __restrict__ b_my,
    const float* __restrict__ W_fi, const float* __restrict__ b_fi,
    const float* __restrict__ W_he, const float* __restrict__ b_he,
    const float* __restrict__ W_ra, const float* __restrict__ b_ra,
    const float* __restrict__ W_rb, const float* __restrict__ b_rb,
    float* out)   // aliases the combined staging area — no __restrict__
{
    const int t = threadIdx.x;
    const int r0 = blockIdx.x * BB;

    __shared__ float s_x[BB][128];   // combined -> reactive -> h
    __shared__ float s_y[BB][128];   // r1 -> features
    __shared__ float s_hx[BB][128];
    __shared__ float s_g[BB][512];   // gates

    for (int idx = t; idx < BB * 128; idx += 256) {
        const int r = idx >> 7, j = idx & 127;
        s_x[r][j]  = out[(size_t)(r0 + r) * 268 + 12 + j];
        s_hx[r][j] = hx[(size_t)(r0 + r) * 128 + j];
    }
    __syncthreads();

    gemv128(s_x, s_y, W_p1, b_p1, t, true);    // r1
    __syncthreads();
    gemv128(s_y, s_x, W_p2, b_p2, t, true);    // reactive
    __syncthreads();

    // ---- LSTM gates: thread t owns output cols t and t+256 across all 16 rows
    {
        float acc1[16], acc2[16];
        const float bs1 = b_ih[t] + b_hh[t];
        const float bs2 = b_ih[t + 256] + b_hh[t + 256];
        #pragma unroll
        for (int r = 0; r < 16; ++r) { acc1[r] = bs1; acc2[r] = bs2; }
        #pragma unroll 4
        for (int i = 0; i < 128; ++i) {
            const float w1 = W_ih[i * 512 + t];
            const float w2 = W_ih[i * 512 + t + 256];
            #pragma unroll
            for (int r = 0; r < 16; ++r) {
                const float x = s_x[r][i];
                acc1[r] = fmaf(x, w1, acc1[r]);
                acc2[r] = fmaf(x, w2, acc2[r]);
            }
        }
        #pragma unroll 4
        for (int i = 0; i < 128; ++i) {
            const float w1 = W_hh[i * 512 + t];
            const float w2 = W_hh[i * 512 + t + 256];
            #pragma unroll
            for (int r = 0; r < 16; ++r) {
                const float x = s_hx[r][i];
                acc1[r] = fmaf(x, w1, acc1[r]);
                acc2[r] = fmaf(x, w2, acc2[r]);
            }
        }
        #pragma unroll
        for (int r = 0; r < 16; ++r) { s_g[r][t] = acc1[r]; s_g[r][t + 256] = acc2[r]; }
    }
    __syncthreads();

    // ---- LSTM elementwise (gate order i,f,g,o)
    for (int idx = t; idx < BB * 128; idx += 256) {
        const int r = idx >> 7, j = idx & 127;
        const float ig = s_g[r][j];
        const float fg = s_g[r][j + 128];
        const float gg = s_g[r][j + 256];
        const float og = s_g[r][j + 384];
        const float c_old = cx[(size_t)(r0 + r) * 128 + j];
        const float c_new = sigf(fg) * c_old + sigf(ig) * tanhf(gg);
        const float h_new = sigf(og) * tanhf(c_new);
        out[(size_t)(r0 + r) * 268 + 12 + j]  = h_new;
        out[(size_t)(r0 + r) * 268 + 140 + j] = c_new;
        s_y[r][j] = s_x[r][j] + h_new;   // features = reactive + hx_new
    }
    __syncthreads();

    gemv128(s_y, s_x, W_a, b_a, t, true);      // h
    __syncthreads();

    // ---- small heads: 12 scalar outputs per row
    if (t < BB * 12) {
        const int r = t / 12, w = t % 12;
        const float* Wm; const float* bm; int nc, c, off;
        if (w < 3)       { Wm = W_mx; bm = b_mx; nc = 3; c = w;     off = w;  }
        else if (w < 6)  { Wm = W_my; bm = b_my; nc = 3; c = w - 3; off = w;  }
        else if (w < 8)  { Wm = W_fi; bm = b_fi; nc = 2; c = w - 6; off = w;  }
        else if (w < 10) { Wm = W_he; bm = b_he; nc = 2; c = w - 8; off = w;  }
        else if (w == 10){ Wm = W_ra; bm = b_ra; nc = 1; c = 0;     off = 10; }
        else             { Wm = W_rb; bm = b_rb; nc = 1; c = 0;     off = 11; }
        float acc = bm[c];
        for (int i = 0; i < 128; ++i) acc = fmaf(s_x[r][i], Wm[i * nc + c], acc);
        if (w >= 10) acc = fmaxf(acc, 0.0f) + log1pf(__expf(-fabsf(acc))) + 1.0f;
        out[(size_t)(r0 + r) * 268 + off] = acc;
    }
}

extern "C" void kernel_launch(void* const* d_in, const int* in_sizes, int n_in,
                              void* d_out, int out_size, void* d_ws, size_t ws_size,
                              hipStream_t stream) {
    (void)n_in; (void)out_size; (void)d_ws; (void)ws_size;
    const float* self_feat = (const float*)d_in[0];
    const float* entities  = (const float*)d_in[1];
    const void*  mask      = d_in[2];
    const float* hx  = (const float*)d_in[3];
    const float* cx  = (const float*)d_in[4];
    const float* W_se = (const float*)d_in[5],  *b_se = (const float*)d_in[6];
    const float* W_ee = (const float*)d_in[7],  *b_ee = (const float*)d_in[8];
    const float* W_q  = (const float*)d_in[9],  *b_q  = (const float*)d_in[10];
    const float* W_k  = (const float*)d_in[11], *b_k  = (const float*)d_in[12];
    const float* W_v  = (const float*)d_in[13], *b_v  = (const float*)d_in[14];
    const float* W_p1 = (const float*)d_in[15], *b_p1 = (const float*)d_in[16];
    const float* W_p2 = (const float*)d_in[17], *b_p2 = (const float*)d_in[18];
    const float* W_ih = (const float*)d_in[19], *b_ih = (const float*)d_in[20];
    const float* W_hh = (const float*)d_in[21], *b_hh = (const float*)d_in[22];
    const float* W_a  = (const float*)d_in[23], *b_a  = (const float*)d_in[24];
    const float* W_mx = (const float*)d_in[25], *b_mx = (const float*)d_in[26];
    const float* W_my = (const float*)d_in[27], *b_my = (const float*)d_in[28];
    const float* W_fi = (const float*)d_in[29], *b_fi = (const float*)d_in[30];
    const float* W_he = (const float*)d_in[31], *b_he = (const float*)d_in[32];
    const float* W_ra = (const float*)d_in[33], *b_ra = (const float*)d_in[34];
    const float* W_rb = (const float*)d_in[35], *b_rb = (const float*)d_in[36];
    float* out = (float*)d_out;

    const int B = in_sizes[0] / 24;   // 8192

    ka_attention_v3<<<B, 256, 0, stream>>>(self_feat, entities, mask,
        W_se, b_se, W_ee, b_ee, W_q, b_q, W_k, b_k, W_v, b_v, out);
    kb_lstm_heads<<<B / BB, 256, 0, stream>>>(hx, cx,
        W_p1, b_p1, W_p2, b_p2, W_ih, b_ih, W_hh, b_hh, W_a, b_a,
        W_mx, b_mx, W_my, b_my, W_fi, b_fi, W_he, b_he, W_ra, b_ra, W_rb, b_rb, out);
}

// Round 8
// 196.313 us; speedup vs baseline: 4.8281x; 1.2236x over previous
//
#include <hip/hip_runtime.h>
#include <math.h>

#define BB 16

typedef __attribute__((ext_vector_type(8))) unsigned short ushort8;

__device__ __forceinline__ float sigf(float x) { return 1.0f / (1.0f + __expf(-x)); }

__device__ __forceinline__ float bf2f(unsigned short s) {
    return __uint_as_float(((unsigned int)s) << 16);
}
__device__ __forceinline__ unsigned short f2bf(float f) {   // round-to-nearest (no tie fix)
    return (unsigned short)((__float_as_uint(f) + 0x8000u) >> 16);
}

// ---------------- Kernel A v4: reduced attention, latency-restructured.
// One row per 256-thread block. All HBM loads issued up front; entities staged
// per-wave (wave-private -> encode needs no barrier); emb/q/qb computed inside
// wave 0 while waves 1-3 encode; 6 barriers total; conflict-free score swizzle.
__global__ __launch_bounds__(256) void ka_attention_v4(
    const float* __restrict__ self_feat,   // (B,24)
    const float* __restrict__ entities,    // (B,128,12)
    const void*  __restrict__ mask_raw,    // (B,128) int32 or uint8
    const float* __restrict__ W_se, const float* __restrict__ b_se,
    const float* __restrict__ W_ee, const float* __restrict__ b_ee,
    const float* __restrict__ W_q,  const float* __restrict__ b_q,
    const float* __restrict__ W_k,  const float* __restrict__ b_k,
    const float* __restrict__ W_v,  const float* __restrict__ b_v,
    float* out)                            // (B,268)
{
    const int t = threadIdx.x;
    const int l = t & 63;
    const int w = __builtin_amdgcn_readfirstlane(t >> 6);   // wave id 0..3
    const int b = blockIdx.x;

    __shared__ __align__(16) float s_ent[1536];      // 6 KB; overlaid by ctxp/ctx later
    __shared__ unsigned short s_eet[4][2048];        // 16 KB, wave-private bf16 32x64 tiles
    __shared__ __align__(16) float s_p[128 * 4];     // scores -> attn, [n][h]
    __shared__ __align__(16) float s_qk[64 * 4];     // qkh [i][h]
    __shared__ float s_q[64];
    __shared__ float s_emb[64];
    __shared__ __align__(16) float s_qb[4];
    float* s_ctxp = s_ent;                           // [w][i][h] 4 KB (s_ent dead by then)
    float* s_ctx  = s_ent + 1024;                    // [i][h]    1 KB

    // ---- A: issue entity staging loads (own wave region, coalesced float4)
    const float4* ef = (const float4*)(entities + (size_t)b * 1536);
    const float4 st0 = ef[w * 96 + l];
    float4 st1;
    if (l < 32) st1 = ef[w * 96 + 64 + l];

    // ---- mask dtype probe (uniform scalar loads) + early per-entity mask load
    bool mask_is_int = true;
    {
        const unsigned int* mw = (const unsigned int*)mask_raw;
        #pragma unroll
        for (int w0 = 0; w0 < 64; ++w0) mask_is_int = mask_is_int && (mw[w0] <= 1u);
    }
    bool msk;
    {
        const int ng = w * 32 + (l & 31);
        if (mask_is_int) msk = ((const int*)mask_raw)[(size_t)b * 128 + ng] != 0;
        else             msk = ((const unsigned char*)mask_raw)[(size_t)b * 128 + ng] != 0;
    }

    // ---- B: wave 0 computes emb, q, qb (wave-private LDS, no barrier needed)
    float emb = 0.0f;
    if (w == 0) {
        const float4* sf = (const float4*)(self_feat + (size_t)b * 24);
        const float4 s0 = sf[0], s1 = sf[1], s2 = sf[2];
        const float4 s3 = sf[3], s4 = sf[4], s5 = sf[5];
        float a = b_se[l];
        a = fmaf(s0.x, W_se[0*64+l], a);  a = fmaf(s0.y, W_se[1*64+l], a);
        a = fmaf(s0.z, W_se[2*64+l], a);  a = fmaf(s0.w, W_se[3*64+l], a);
        a = fmaf(s1.x, W_se[4*64+l], a);  a = fmaf(s1.y, W_se[5*64+l], a);
        a = fmaf(s1.z, W_se[6*64+l], a);  a = fmaf(s1.w, W_se[7*64+l], a);
        a = fmaf(s2.x, W_se[8*64+l], a);  a = fmaf(s2.y, W_se[9*64+l], a);
        a = fmaf(s2.z, W_se[10*64+l], a); a = fmaf(s2.w, W_se[11*64+l], a);
        a = fmaf(s3.x, W_se[12*64+l], a); a = fmaf(s3.y, W_se[13*64+l], a);
        a = fmaf(s3.z, W_se[14*64+l], a); a = fmaf(s3.w, W_se[15*64+l], a);
        a = fmaf(s4.x, W_se[16*64+l], a); a = fmaf(s4.y, W_se[17*64+l], a);
        a = fmaf(s4.z, W_se[18*64+l], a); a = fmaf(s4.w, W_se[19*64+l], a);
        a = fmaf(s5.x, W_se[20*64+l], a); a = fmaf(s5.y, W_se[21*64+l], a);
        a = fmaf(s5.z, W_se[22*64+l], a); a = fmaf(s5.w, W_se[23*64+l], a);
        emb = fmaxf(a, 0.0f);
        s_emb[l] = emb;                      // wave-private scratch
        float qv = b_q[l];
        #pragma unroll 8
        for (int i = 0; i < 64; ++i) qv = fmaf(s_emb[i], W_q[i * 64 + l], qv);
        s_q[l] = qv;
        float v = qv * b_k[l];
        v += __shfl_xor(v, 1); v += __shfl_xor(v, 2);
        v += __shfl_xor(v, 4); v += __shfl_xor(v, 8);
        if ((l & 15) == 0) s_qb[l >> 4] = v;
    }

    // ---- C: stage to LDS + encode own 32 entities (wave-private, no barrier)
    *(float4*)&s_ent[(w * 96 + l) * 4] = st0;
    if (l < 32) *(float4*)&s_ent[(w * 96 + 64 + l) * 4] = st1;

    float eev[32];
    {
        float wee[12];
        #pragma unroll
        for (int i = 0; i < 12; ++i) wee[i] = W_ee[i * 64 + l];
        const float bee = b_ee[l];
        unsigned short* tile = s_eet[w];
        #pragma unroll 8
        for (int j = 0; j < 32; ++j) {
            const float* en = s_ent + (w * 32 + j) * 12;     // uniform broadcast reads
            const float4 e0 = *(const float4*)(en);
            const float4 e1 = *(const float4*)(en + 4);
            const float4 e2 = *(const float4*)(en + 8);
            float a = bee;
            a = fmaf(e0.x, wee[0], a);  a = fmaf(e0.y, wee[1], a);
            a = fmaf(e0.z, wee[2], a);  a = fmaf(e0.w, wee[3], a);
            a = fmaf(e1.x, wee[4], a);  a = fmaf(e1.y, wee[5], a);
            a = fmaf(e1.z, wee[6], a);  a = fmaf(e1.w, wee[7], a);
            a = fmaf(e2.x, wee[8], a);  a = fmaf(e2.y, wee[9], a);
            a = fmaf(e2.z, wee[10], a); a = fmaf(e2.w, wee[11], a);
            a = fmaxf(a, 0.0f);
            eev[j] = a;
            // conflict-free swizzle: read bank-quad = (i8>>3) ^ (n&7), distinct per phase
            tile[j * 64 + (l ^ ((j & 7) << 3))] = f2bf(a);
        }
    }
    __syncthreads();   // #1: s_q/s_qb ready (s_eet/s_ent are wave-private)

    // ---- D: qkh cooperative: i = lane, head = wave
    {
        const float* wkrow = W_k + l * 64 + w * 16;
        const float4 k0 = *(const float4*)(wkrow);
        const float4 k1 = *(const float4*)(wkrow + 4);
        const float4 k2 = *(const float4*)(wkrow + 8);
        const float4 k3 = *(const float4*)(wkrow + 12);
        float acc = 0.0f;
        acc = fmaf(k0.x, s_q[w * 16 + 0],  acc); acc = fmaf(k0.y, s_q[w * 16 + 1],  acc);
        acc = fmaf(k0.z, s_q[w * 16 + 2],  acc); acc = fmaf(k0.w, s_q[w * 16 + 3],  acc);
        acc = fmaf(k1.x, s_q[w * 16 + 4],  acc); acc = fmaf(k1.y, s_q[w * 16 + 5],  acc);
        acc = fmaf(k1.z, s_q[w * 16 + 6],  acc); acc = fmaf(k1.w, s_q[w * 16 + 7],  acc);
        acc = fmaf(k2.x, s_q[w * 16 + 8],  acc); acc = fmaf(k2.y, s_q[w * 16 + 9],  acc);
        acc = fmaf(k2.z, s_q[w * 16 + 10], acc); acc = fmaf(k2.w, s_q[w * 16 + 11], acc);
        acc = fmaf(k3.x, s_q[w * 16 + 12], acc); acc = fmaf(k3.y, s_q[w * 16 + 13], acc);
        acc = fmaf(k3.z, s_q[w * 16 + 14], acc); acc = fmaf(k3.w, s_q[w * 16 + 15], acc);
        s_qk[l * 4 + w] = acc;
    }
    __syncthreads();   // #2: s_qk ready

    // ---- E: scores for own 32 entities (lane n = l&31, i split across halves)
    {
        const int n_l = l & 31, ihalf = l >> 5;
        float sc0 = 0.f, sc1 = 0.f, sc2 = 0.f, sc3 = 0.f;
        #pragma unroll
        for (int blk = 0; blk < 4; ++blk) {
            const int i8 = ihalf * 32 + blk * 8;
            const ushort8 ev = *(const ushort8*)&s_eet[w][n_l * 64 + (i8 ^ ((n_l & 7) << 3))];
            #pragma unroll
            for (int k = 0; k < 8; ++k) {
                const float e = bf2f(ev[k]);
                const float4 qk = *(const float4*)&s_qk[(i8 + k) * 4];   // uniform b128
                sc0 = fmaf(e, qk.x, sc0); sc1 = fmaf(e, qk.y, sc1);
                sc2 = fmaf(e, qk.z, sc2); sc3 = fmaf(e, qk.w, sc3);
            }
        }
        sc0 += __shfl_xor(sc0, 32); sc1 += __shfl_xor(sc1, 32);
        sc2 += __shfl_xor(sc2, 32); sc3 += __shfl_xor(sc3, 32);

        const float4 qbv = *(const float4*)s_qb;
        sc0 = msk ? (sc0 + qbv.x) * 0.25f : -1e30f;
        sc1 = msk ? (sc1 + qbv.y) * 0.25f : -1e30f;
        sc2 = msk ? (sc2 + qbv.z) * 0.25f : -1e30f;
        sc3 = msk ? (sc3 + qbv.w) * 0.25f : -1e30f;
        if (l < 32) {
            float4 s4; s4.x = sc0; s4.y = sc1; s4.z = sc2; s4.w = sc3;
            *(float4*)&s_p[(w * 32 + n_l) * 4] = s4;
        }
    }
    __syncthreads();   // #3: s_p (scores) ready

    // ---- F: softmax, wave w = head w over 128 entities (2 per lane)
    {
        float sc0 = s_p[l * 4 + w];
        float sc1 = s_p[(l + 64) * 4 + w];
        float mx = fmaxf(sc0, sc1);
        #pragma unroll
        for (int d = 1; d < 64; d <<= 1) mx = fmaxf(mx, __shfl_xor(mx, d));
        const float e0 = __expf(sc0 - mx), e1 = __expf(sc1 - mx);
        float sm = e0 + e1;
        #pragma unroll
        for (int d = 1; d < 64; d <<= 1) sm += __shfl_xor(sm, d);
        const float inv = 1.0f / sm;
        s_p[l * 4 + w]        = e0 * inv;
        s_p[(l + 64) * 4 + w] = e1 * inv;
    }
    __syncthreads();   // #4: attn ready

    // ---- G: ctx partials from register ee (lane = dim i)
    {
        float c0 = 0.f, c1 = 0.f, c2 = 0.f, c3 = 0.f;
        #pragma unroll
        for (int j = 0; j < 32; ++j) {
            const float4 pv = *(const float4*)&s_p[(w * 32 + j) * 4];    // uniform b128
            c0 = fmaf(pv.x, eev[j], c0);
            c1 = fmaf(pv.y, eev[j], c1);
            c2 = fmaf(pv.z, eev[j], c2);
            c3 = fmaf(pv.w, eev[j], c3);
        }
        float4 cv; cv.x = c0; cv.y = c1; cv.z = c2; cv.w = c3;
        *(float4*)&s_ctxp[(w * 64 + l) * 4] = cv;          // [w][i][h], conflict-free
    }
    __syncthreads();   // #5: ctx partials ready

    // ---- H: ctx sum, thread t -> (i = t>>2, h = t&3); 2-way (free) bank pattern
    {
        const int i = t >> 2, h = t & 3;
        s_ctx[i * 4 + h] = s_ctxp[(0 * 64 + i) * 4 + h] + s_ctxp[(1 * 64 + i) * 4 + h]
                         + s_ctxp[(2 * 64 + i) * 4 + h] + s_ctxp[(3 * 64 + i) * 4 + h];
    }
    __syncthreads();   // #6: ctx ready

    // ---- I: wave-0 tail: attn_out projection + output writes (others exit)
    if (w == 0) {
        const int h = l >> 4;
        float ao = b_v[l];
        #pragma unroll 8
        for (int i = 0; i < 64; ++i) ao = fmaf(s_ctx[i * 4 + h], W_v[i * 64 + l], ao);
        out[(size_t)b * 268 + 12 + l] = emb;   // combined[0:64)
        out[(size_t)b * 268 + 76 + l] = ao;    // combined[64:128)
    }
}

// 128x128 GEMV over BB rows staged in LDS; weights from global (L2-resident).
__device__ __forceinline__ void gemv128(const float (*s_in)[128], float (*s_out)[128],
                                        const float* __restrict__ W,
                                        const float* __restrict__ bvec,
                                        int t, bool relu_)
{
    const int oo = t & 127;
    const int rb = (t >> 7) * 8;
    const float bv = bvec[oo];
    float acc[8];
    #pragma unroll
    for (int r = 0; r < 8; ++r) acc[r] = bv;
    #pragma unroll 4
    for (int i = 0; i < 128; ++i) {
        const float w = W[i * 128 + oo];
        #pragma unroll
        for (int r = 0; r < 8; ++r) acc[r] = fmaf(s_in[rb + r][i], w, acc[r]);
    }
    #pragma unroll
    for (int r = 0; r < 8; ++r) s_out[rb + r][oo] = relu_ ? fmaxf(acc[r], 0.0f) : acc[r];
}

// ---------------- Kernel B: MLP + LSTM + actor heads (16 rows per block)
__global__ __launch_bounds__(256) void kb_lstm_heads(
    const float* __restrict__ hx, const float* __restrict__ cx,
    const float* __restrict__ W_p1, const float* __restrict__ b_p1,
    const float* __restrict__ W_p2, const float* __restrict__ b_p2,
    const float* __restrict__ W_ih, const float* __restrict__ b_ih,
    const float* __restrict__ W_hh, const float* __restrict__ b_hh,
    const float* __restrict__ W_a,  const float* __restrict__ b_a,
    const float* __restrict__ W_mx, const float* __restrict__ b_mx,
    const float* __restrict__ W_my, const float* __restrict__ b_my,
    const float* __restrict__ W_fi, const float* __restrict__ b_fi,
    const float* __restrict__ W_he, const float* __restrict__ b_he,
    const float* __restrict__ W_ra, const float* __restrict__ b_ra,
    const float* __restrict__ W_rb, const float* __restrict__ b_rb,
    float* out)   // aliases the combined staging area — no __restrict__
{
    const int t = threadIdx.x;
    const int r0 = blockIdx.x * BB;

    __shared__ float s_x[BB][128];   // combined -> reactive -> h
    __shared__ float s_y[BB][128];   // r1 -> features
    __shared__ float s_hx[BB][128];
    __shared__ float s_g[BB][512];   // gates

    for (int idx = t; idx < BB * 128; idx += 256) {
        const int r = idx >> 7, j = idx & 127;
        s_x[r][j]  = out[(size_t)(r0 + r) * 268 + 12 + j];
        s_hx[r][j] = hx[(size_t)(r0 + r) * 128 + j];
    }
    __syncthreads();

    gemv128(s_x, s_y, W_p1, b_p1, t, true);    // r1
    __syncthreads();
    gemv128(s_y, s_x, W_p2, b_p2, t, true);    // reactive
    __syncthreads();

    // ---- LSTM gates: thread t owns output cols t and t+256 across all 16 rows
    {
        float acc1[16], acc2[16];
        const float bs1 = b_ih[t] + b_hh[t];
        const float bs2 = b_ih[t + 256] + b_hh[t + 256];
        #pragma unroll
        for (int r = 0; r < 16; ++r) { acc1[r] = bs1; acc2[r] = bs2; }
        #pragma unroll 4
        for (int i = 0; i < 128; ++i) {
            const float w1 = W_ih[i * 512 + t];
            const float w2 = W_ih[i * 512 + t + 256];
            #pragma unroll
            for (int r = 0; r < 16; ++r) {
                const float x = s_x[r][i];
                acc1[r] = fmaf(x, w1, acc1[r]);
                acc2[r] = fmaf(x, w2, acc2[r]);
            }
        }
        #pragma unroll 4
        for (int i = 0; i < 128; ++i) {
            const float w1 = W_hh[i * 512 + t];
            const float w2 = W_hh[i * 512 + t + 256];
            #pragma unroll
            for (int r = 0; r < 16; ++r) {
                const float x = s_hx[r][i];
                acc1[r] = fmaf(x, w1, acc1[r]);
                acc2[r] = fmaf(x, w2, acc2[r]);
            }
        }
        #pragma unroll
        for (int r = 0; r < 16; ++r) { s_g[r][t] = acc1[r]; s_g[r][t + 256] = acc2[r]; }
    }
    __syncthreads();

    // ---- LSTM elementwise (gate order i,f,g,o)
    for (int idx = t; idx < BB * 128; idx += 256) {
        const int r = idx >> 7, j = idx & 127;
        const float ig = s_g[r][j];
        const float fg = s_g[r][j + 128];
        const float gg = s_g[r][j + 256];
        const float og = s_g[r][j + 384];
        const float c_old = cx[(size_t)(r0 + r) * 128 + j];
        const float c_new = sigf(fg) * c_old + sigf(ig) * tanhf(gg);
        const float h_new = sigf(og) * tanhf(c_new);
        out[(size_t)(r0 + r) * 268 + 12 + j]  = h_new;
        out[(size_t)(r0 + r) * 268 + 140 + j] = c_new;
        s_y[r][j] = s_x[r][j] + h_new;   // features = reactive + hx_new
    }
    __syncthreads();

    gemv128(s_y, s_x, W_a, b_a, t, true);      // h
    __syncthreads();

    // ---- small heads: 12 scalar outputs per row
    if (t < BB * 12) {
        const int r = t / 12, w = t % 12;
        const float* Wm; const float* bm; int nc, c, off;
        if (w < 3)       { Wm = W_mx; bm = b_mx; nc = 3; c = w;     off = w;  }
        else if (w < 6)  { Wm = W_my; bm = b_my; nc = 3; c = w - 3; off = w;  }
        else if (w < 8)  { Wm = W_fi; bm = b_fi; nc = 2; c = w - 6; off = w;  }
        else if (w < 10) { Wm = W_he; bm = b_he; nc = 2; c = w - 8; off = w;  }
        else if (w == 10){ Wm = W_ra; bm = b_ra; nc = 1; c = 0;     off = 10; }
        else             { Wm = W_rb; bm = b_rb; nc = 1; c = 0;     off = 11; }
        float acc = bm[c];
        for (int i = 0; i < 128; ++i) acc = fmaf(s_x[r][i], Wm[i * nc + c], acc);
        if (w >= 10) acc = fmaxf(acc, 0.0f) + log1pf(__expf(-fabsf(acc))) + 1.0f;
        out[(size_t)(r0 + r) * 268 + off] = acc;
    }
}

extern "C" void kernel_launch(void* const* d_in, const int* in_sizes, int n_in,
                              void* d_out, int out_size, void* d_ws, size_t ws_size,
                              hipStream_t stream) {
    (void)n_in; (void)out_size; (void)d_ws; (void)ws_size;
    const float* self_feat = (const float*)d_in[0];
    const float* entities  = (const float*)d_in[1];
    const void*  mask      = d_in[2];
    const float* hx  = (const float*)d_in[3];
    const float* cx  = (const float*)d_in[4];
    const float* W_se = (const float*)d_in[5],  *b_se = (const float*)d_in[6];
    const float* W_ee = (const float*)d_in[7],  *b_ee = (const float*)d_in[8];
    const float* W_q  = (const float*)d_in[9],  *b_q  = (const float*)d_in[10];
    const float* W_k  = (const float*)d_in[11], *b_k  = (const float*)d_in[12];
    const float* W_v  = (const float*)d_in[13], *b_v  = (const float*)d_in[14];
    const float* W_p1 = (const float*)d_in[15], *b_p1 = (const float*)d_in[16];
    const float* W_p2 = (const float*)d_in[17], *b_p2 = (const float*)d_in[18];
    const float* W_ih = (const float*)d_in[19], *b_ih = (const float*)d_in[20];
    const float* W_hh = (const float*)d_in[21], *b_hh = (const float*)d_in[22];
    const float* W_a  = (const float*)d_in[23], *b_a  = (const float*)d_in[24];
    const float* W_mx = (const float*)d_in[25], *b_mx = (const float*)d_in[26];
    const float* W_my = (const float*)d_in[27], *b_my = (const float*)d_in[28];
    const float* W_fi = (const float*)d_in[29], *b_fi = (const float*)d_in[30];
    const float* W_he = (const float*)d_in[31], *b_he = (const float*)d_in[32];
    const float* W_ra = (const float*)d_in[33], *b_ra = (const float*)d_in[34];
    const float* W_rb = (const float*)d_in[35], *b_rb = (const float*)d_in[36];
    float* out = (float*)d_out;

    const int B = in_sizes[0] / 24;   // 8192

    ka_attention_v4<<<B, 256, 0, stream>>>(self_feat, entities, mask,
        W_se, b_se, W_ee, b_ee, W_q, b_q, W_k, b_k, W_v, b_v, out);
    kb_lstm_heads<<<B / BB, 256, 0, stream>>>(hx, cx,
        W_p1, b_p1, W_p2, b_p2, W_ih, b_ih, W_hh, b_hh, W_a, b_a,
        W_mx, b_mx, W_my, b_my, W_fi, b_fi, W_he, b_he, W_ra, b_ra, W_rb, b_rb, out);
}

// Round 9
// 159.220 us; speedup vs baseline: 5.9529x; 1.2330x over previous
//
#include <hip/hip_runtime.h>
#include <math.h>

#define BB 16

typedef __attribute__((ext_vector_type(8))) unsigned short ushort8;

__device__ __forceinline__ float sigf(float x) { return 1.0f / (1.0f + __expf(-x)); }

__device__ __forceinline__ float bf2f(unsigned short s) {
    return __uint_as_float(((unsigned int)s) << 16);
}
__device__ __forceinline__ unsigned short f2bf(float f) {
    return (unsigned short)((__float_as_uint(f) + 0x8000u) >> 16);
}

#define WAVE_WAIT() asm volatile("s_waitcnt lgkmcnt(0)" ::: "memory")

// ---------------- Kernel A v5: one WAVE per row, zero block barriers in the
// per-row path. Flash over 2 passes of 64 entities; lane=entity for encode+
// scores (W_ee uniform from LDS), bf16 tile only for the ctx transpose.
__global__ __launch_bounds__(256) void ka_attention_v5(
    const float* __restrict__ self_feat,   // (B,24)
    const float* __restrict__ entities,    // (B,128,12)
    const void*  __restrict__ mask_raw,    // (B,128) int32 or uint8
    const float* __restrict__ W_se, const float* __restrict__ b_se,
    const float* __restrict__ W_ee, const float* __restrict__ b_ee,
    const float* __restrict__ W_q,  const float* __restrict__ b_q,
    const float* __restrict__ W_k,  const float* __restrict__ b_k,
    const float* __restrict__ W_v,  const float* __restrict__ b_v,
    float* out)                            // (B,268)
{
    const int t = threadIdx.x;
    const int l = t & 63;
    const int w = __builtin_amdgcn_readfirstlane(t >> 6);   // wave id = row within block
    const int b = blockIdx.x * 4 + w;

    __shared__ float s_wee[768];                              // 3 KB, block-shared
    __shared__ __align__(16) unsigned short s_tile[4][64][64];// 32 KB, wave-private
    __shared__ __align__(16) float s_qk[4][64][4];            // qkh [i][h]
    __shared__ __align__(16) float s_p[4][64][4];             // tile weights [n][h]
    __shared__ __align__(16) float s_ctx[4][64][4];           // ctx [i][h]
    __shared__ float s_emb[4][64];
    __shared__ float s_q[4][64];

    // ---- stage W_ee (global layout [i][d]) cooperatively
    s_wee[t]       = W_ee[t];
    s_wee[t + 256] = W_ee[t + 256];
    s_wee[t + 512] = W_ee[t + 512];

    // ---- mask dtype probe (uniform scalar loads)
    bool mask_is_int = true;
    {
        const unsigned int* mw = (const unsigned int*)mask_raw;
        #pragma unroll
        for (int w0 = 0; w0 < 64; ++w0) mask_is_int = mask_is_int && (mw[w0] <= 1u);
    }

    __syncthreads();   // the ONLY block barrier: s_wee ready

    // ================= per-wave (one row) from here =================

    // ---- self_embed (lane = dim)
    float emb = b_se[l];
    {
        const float* sfp = self_feat + (size_t)b * 24;
        #pragma unroll
        for (int i = 0; i < 24; ++i) emb = fmaf(sfp[i], W_se[i * 64 + l], emb);
        emb = fmaxf(emb, 0.0f);
    }
    s_emb[w][l] = emb;
    WAVE_WAIT();

    // ---- q (lane = dim): emb uniform from LDS, W_q coalesced
    float qv = b_q[l];
    #pragma unroll
    for (int i4 = 0; i4 < 16; ++i4) {
        const float4 ev = *(const float4*)&s_emb[w][i4 * 4];
        qv = fmaf(ev.x, W_q[(i4 * 4 + 0) * 64 + l], qv);
        qv = fmaf(ev.y, W_q[(i4 * 4 + 1) * 64 + l], qv);
        qv = fmaf(ev.z, W_q[(i4 * 4 + 2) * 64 + l], qv);
        qv = fmaf(ev.w, W_q[(i4 * 4 + 3) * 64 + l], qv);
    }
    s_q[w][l] = qv;

    // ---- qb[h] = sum_{d in head h} q[d]*b_k[d], broadcast to all lanes
    float vb = qv * b_k[l];
    vb += __shfl_xor(vb, 1); vb += __shfl_xor(vb, 2);
    vb += __shfl_xor(vb, 4); vb += __shfl_xor(vb, 8);
    const float qb0 = __shfl(vb, 0),  qb1 = __shfl(vb, 16);
    const float qb2 = __shfl(vb, 32), qb3 = __shfl(vb, 48);
    WAVE_WAIT();

    // ---- qkh[i][h]: lane (i=l>>2, h=l&3) owns a contiguous 64B quarter-row of
    // W_k -> fully coalesced. 4 i-groups of 16.
    {
        const int hh = l & 3;
        #pragma unroll
        for (int g = 0; g < 4; ++g) {
            const int i = g * 16 + (l >> 2);
            const float* wk = W_k + i * 64 + hh * 16;
            float acc = 0.0f;
            #pragma unroll
            for (int j4 = 0; j4 < 4; ++j4) {
                const float4 kv = *(const float4*)(wk + j4 * 4);
                const float4 qq = *(const float4*)&s_q[w][hh * 16 + j4 * 4];
                acc = fmaf(kv.x, qq.x, acc); acc = fmaf(kv.y, qq.y, acc);
                acc = fmaf(kv.z, qq.z, acc); acc = fmaf(kv.w, qq.w, acc);
            }
            s_qk[w][i][hh] = acc;
        }
    }

    // ---- flash state (replicated across lanes) + ctx accumulators (lane = dim)
    float m0 = -1e30f, m1 = -1e30f, m2 = -1e30f, m3 = -1e30f;
    float ll0 = 0.f, ll1 = 0.f, ll2 = 0.f, ll3 = 0.f;
    float ctx0 = 0.f, ctx1 = 0.f, ctx2 = 0.f, ctx3 = 0.f;

    const float4* beev = (const float4*)b_ee;

    #pragma unroll 1
    for (int pass = 0; pass < 2; ++pass) {
        const int n = pass * 64 + l;     // lane = entity

        bool msk;
        if (mask_is_int) msk = ((const int*)mask_raw)[(size_t)b * 128 + n] != 0;
        else             msk = ((const unsigned char*)mask_raw)[(size_t)b * 128 + n] != 0;

        const float* ep = entities + (size_t)b * 1536 + n * 12;
        const float4 e0 = *(const float4*)ep;
        const float4 e1 = *(const float4*)(ep + 4);
        const float4 e2 = *(const float4*)(ep + 8);

        // -- encode own entity: ee[d] d=0..63 in 16 float4 accumulators
        float4 ee4[16];
        #pragma unroll
        for (int d4 = 0; d4 < 16; ++d4) ee4[d4] = beev[d4];
        #define ENC(EIV, ROW)                                                  \
            { const float eiv_ = (EIV);                                        \
              _Pragma("unroll")                                                \
              for (int d4 = 0; d4 < 16; ++d4) {                                \
                  const float4 wv = *(const float4*)&s_wee[(ROW) * 64 + d4*4]; \
                  ee4[d4].x = fmaf(eiv_, wv.x, ee4[d4].x);                     \
                  ee4[d4].y = fmaf(eiv_, wv.y, ee4[d4].y);                     \
                  ee4[d4].z = fmaf(eiv_, wv.z, ee4[d4].z);                     \
                  ee4[d4].w = fmaf(eiv_, wv.w, ee4[d4].w); } }
        ENC(e0.x, 0)  ENC(e0.y, 1)  ENC(e0.z, 2)  ENC(e0.w, 3)
        ENC(e1.x, 4)  ENC(e1.y, 5)  ENC(e1.z, 6)  ENC(e1.w, 7)
        ENC(e2.x, 8)  ENC(e2.y, 9)  ENC(e2.z, 10) ENC(e2.w, 11)
        #undef ENC

        // -- relu + pack + write own tile row (XOR swizzle on 16B col-groups)
        #pragma unroll
        for (int c8 = 0; c8 < 8; ++c8) {
            const float4 a = ee4[c8 * 2], c = ee4[c8 * 2 + 1];
            ushort8 sv;
            sv[0] = f2bf(fmaxf(a.x, 0.f)); sv[1] = f2bf(fmaxf(a.y, 0.f));
            sv[2] = f2bf(fmaxf(a.z, 0.f)); sv[3] = f2bf(fmaxf(a.w, 0.f));
            sv[4] = f2bf(fmaxf(c.x, 0.f)); sv[5] = f2bf(fmaxf(c.y, 0.f));
            sv[6] = f2bf(fmaxf(c.z, 0.f)); sv[7] = f2bf(fmaxf(c.w, 0.f));
            *(ushort8*)&s_tile[w][l][(c8 ^ (l & 7)) << 3] = sv;
        }
        WAVE_WAIT();   // tile row + s_qk visible to own wave

        // -- scores for own entity (read row back in bf16; frees ee4 regs)
        float sc0 = 0.f, sc1 = 0.f, sc2 = 0.f, sc3 = 0.f;
        #pragma unroll
        for (int c8 = 0; c8 < 8; ++c8) {
            const ushort8 evv = *(const ushort8*)&s_tile[w][l][(c8 ^ (l & 7)) << 3];
            #pragma unroll
            for (int k = 0; k < 8; ++k) {
                const float e = bf2f(evv[k]);
                const float4 qk = *(const float4*)&s_qk[w][c8 * 8 + k][0];
                sc0 = fmaf(e, qk.x, sc0); sc1 = fmaf(e, qk.y, sc1);
                sc2 = fmaf(e, qk.z, sc2); sc3 = fmaf(e, qk.w, sc3);
            }
        }
        sc0 = msk ? (sc0 + qb0) * 0.25f : -1e30f;
        sc1 = msk ? (sc1 + qb1) * 0.25f : -1e30f;
        sc2 = msk ? (sc2 + qb2) * 0.25f : -1e30f;
        sc3 = msk ? (sc3 + qb3) * 0.25f : -1e30f;

        // -- flash update (full-wave reductions -> state replicated)
        float t0 = sc0, t1 = sc1, t2 = sc2, t3 = sc3;
        #pragma unroll
        for (int d = 1; d < 64; d <<= 1) {
            t0 = fmaxf(t0, __shfl_xor(t0, d)); t1 = fmaxf(t1, __shfl_xor(t1, d));
            t2 = fmaxf(t2, __shfl_xor(t2, d)); t3 = fmaxf(t3, __shfl_xor(t3, d));
        }
        const float mn0 = fmaxf(m0, t0), mn1 = fmaxf(m1, t1);
        const float mn2 = fmaxf(m2, t2), mn3 = fmaxf(m3, t3);
        const float sl0 = __expf(m0 - mn0), sl1 = __expf(m1 - mn1);
        const float sl2 = __expf(m2 - mn2), sl3 = __expf(m3 - mn3);
        const float p0 = msk ? __expf(sc0 - mn0) : 0.0f;
        const float p1 = msk ? __expf(sc1 - mn1) : 0.0f;
        const float p2 = msk ? __expf(sc2 - mn2) : 0.0f;
        const float p3 = msk ? __expf(sc3 - mn3) : 0.0f;
        float ps0 = p0, ps1 = p1, ps2 = p2, ps3 = p3;
        #pragma unroll
        for (int d = 1; d < 64; d <<= 1) {
            ps0 += __shfl_xor(ps0, d); ps1 += __shfl_xor(ps1, d);
            ps2 += __shfl_xor(ps2, d); ps3 += __shfl_xor(ps3, d);
        }
        ll0 = ll0 * sl0 + ps0; ll1 = ll1 * sl1 + ps1;
        ll2 = ll2 * sl2 + ps2; ll3 = ll3 * sl3 + ps3;
        m0 = mn0; m1 = mn1; m2 = mn2; m3 = mn3;

        { float4 pv; pv.x = p0; pv.y = p1; pv.z = p2; pv.w = p3;
          *(float4*)&s_p[w][l][0] = pv; }
        WAVE_WAIT();   // p visible

        // -- ctx accumulate (lane = dim l): p uniform, ee from tile column
        ctx0 *= sl0; ctx1 *= sl1; ctx2 *= sl2; ctx3 *= sl3;
        const int cb = (l >> 3) << 3, lo = l & 7;
        #pragma unroll 8
        for (int j = 0; j < 64; ++j) {
            const float4 pj = *(const float4*)&s_p[w][j][0];
            const float e = bf2f(s_tile[w][j][(cb ^ ((j & 7) << 3)) + lo]);
            ctx0 = fmaf(pj.x, e, ctx0); ctx1 = fmaf(pj.y, e, ctx1);
            ctx2 = fmaf(pj.z, e, ctx2); ctx3 = fmaf(pj.w, e, ctx3);
        }
        WAVE_WAIT();   // ctx reads done before next pass overwrites tile
    }

    // ---- finalize: normalize ctx, publish, project with W_v (lane = out dim)
    {
        const float i0 = ll0 > 0.f ? 1.f / ll0 : 0.f;
        const float i1 = ll1 > 0.f ? 1.f / ll1 : 0.f;
        const float i2 = ll2 > 0.f ? 1.f / ll2 : 0.f;
        const float i3 = ll3 > 0.f ? 1.f / ll3 : 0.f;
        float4 cv; cv.x = ctx0 * i0; cv.y = ctx1 * i1; cv.z = ctx2 * i2; cv.w = ctx3 * i3;
        *(float4*)&s_ctx[w][l][0] = cv;
    }
    WAVE_WAIT();
    {
        const int h = l >> 4;
        float ao = b_v[l];
        #pragma unroll 8
        for (int i = 0; i < 64; ++i) ao = fmaf(s_ctx[w][i][h], W_v[i * 64 + l], ao);
        out[(size_t)b * 268 + 12 + l] = emb;   // combined[0:64)
        out[(size_t)b * 268 + 76 + l] = ao;    // combined[64:128)
    }
}

// 128x128 GEMV over 16 rows staged in LDS; 512 threads: 4 row-groups x 128 cols.
__device__ __forceinline__ void gemv128_512(const float (*s_in)[128], float (*s_out)[128],
                                            const float* __restrict__ W,
                                            const float* __restrict__ bvec,
                                            int t, bool relu_)
{
    const int oo = t & 127;
    const int rb = (t >> 7) * 4;
    const float bv = bvec[oo];
    float acc[4];
    #pragma unroll
    for (int r = 0; r < 4; ++r) acc[r] = bv;
    #pragma unroll 4
    for (int i = 0; i < 128; ++i) {
        const float wt = W[i * 128 + oo];
        #pragma unroll
        for (int r = 0; r < 4; ++r) acc[r] = fmaf(s_in[rb + r][i], wt, acc[r]);
    }
    #pragma unroll
    for (int r = 0; r < 4; ++r) s_out[rb + r][oo] = relu_ ? fmaxf(acc[r], 0.0f) : acc[r];
}

// ---------------- Kernel B: MLP + LSTM + actor heads (16 rows, 512 threads)
__global__ __launch_bounds__(512) void kb_lstm_heads(
    const float* __restrict__ hx, const float* __restrict__ cx,
    const float* __restrict__ W_p1, const float* __restrict__ b_p1,
    const float* __restrict__ W_p2, const float* __restrict__ b_p2,
    const float* __restrict__ W_ih, const float* __restrict__ b_ih,
    const float* __restrict__ W_hh, const float* __restrict__ b_hh,
    const float* __restrict__ W_a,  const float* __restrict__ b_a,
    const float* __restrict__ W_mx, const float* __restrict__ b_mx,
    const float* __restrict__ W_my, const float* __restrict__ b_my,
    const float* __restrict__ W_fi, const float* __restrict__ b_fi,
    const float* __restrict__ W_he, const float* __restrict__ b_he,
    const float* __restrict__ W_ra, const float* __restrict__ b_ra,
    const float* __restrict__ W_rb, const float* __restrict__ b_rb,
    float* out)   // aliases the combined staging area — no __restrict__
{
    const int t = threadIdx.x;   // 0..511
    const int r0 = blockIdx.x * BB;

    __shared__ float s_x[BB][128];   // combined -> reactive -> h
    __shared__ float s_y[BB][128];   // r1 -> features
    __shared__ float s_hx[BB][128];
    __shared__ float s_g[BB][512];   // gates

    for (int idx = t; idx < BB * 128; idx += 512) {
        const int r = idx >> 7, j = idx & 127;
        s_x[r][j]  = out[(size_t)(r0 + r) * 268 + 12 + j];
        s_hx[r][j] = hx[(size_t)(r0 + r) * 128 + j];
    }
    __syncthreads();

    gemv128_512(s_x, s_y, W_p1, b_p1, t, true);    // r1
    __syncthreads();
    gemv128_512(s_y, s_x, W_p2, b_p2, t, true);    // reactive
    __syncthreads();

    // ---- LSTM gates: thread t owns output col t (0..511) across all 16 rows
    {
        float acc[16];
        const float bs = b_ih[t] + b_hh[t];
        #pragma unroll
        for (int r = 0; r < 16; ++r) acc[r] = bs;
        #pragma unroll 4
        for (int i = 0; i < 128; ++i) {
            const float w1 = W_ih[i * 512 + t];
            #pragma unroll
            for (int r = 0; r < 16; ++r) acc[r] = fmaf(s_x[r][i], w1, acc[r]);
        }
        #pragma unroll 4
        for (int i = 0; i < 128; ++i) {
            const float w1 = W_hh[i * 512 + t];
            #pragma unroll
            for (int r = 0; r < 16; ++r) acc[r] = fmaf(s_hx[r][i], w1, acc[r]);
        }
        #pragma unroll
        for (int r = 0; r < 16; ++r) s_g[r][t] = acc[r];
    }
    __syncthreads();

    // ---- LSTM elementwise (gate order i,f,g,o)
    for (int idx = t; idx < BB * 128; idx += 512) {
        const int r = idx >> 7, j = idx & 127;
        const float ig = s_g[r][j];
        const float fg = s_g[r][j + 128];
        const float gg = s_g[r][j + 256];
        const float og = s_g[r][j + 384];
        const float c_old = cx[(size_t)(r0 + r) * 128 + j];
        const float c_new = sigf(fg) * c_old + sigf(ig) * tanhf(gg);
        const float h_new = sigf(og) * tanhf(c_new);
        out[(size_t)(r0 + r) * 268 + 12 + j]  = h_new;
        out[(size_t)(r0 + r) * 268 + 140 + j] = c_new;
        s_y[r][j] = s_x[r][j] + h_new;   // features = reactive + hx_new
    }
    __syncthreads();

    gemv128_512(s_y, s_x, W_a, b_a, t, true);      // h
    __syncthreads();

    // ---- small heads: 12 scalar outputs per row
    if (t < BB * 12) {
        const int r = t / 12, ww = t % 12;
        const float* Wm; const float* bm; int nc, c, off;
        if (ww < 3)       { Wm = W_mx; bm = b_mx; nc = 3; c = ww;     off = ww; }
        else if (ww < 6)  { Wm = W_my; bm = b_my; nc = 3; c = ww - 3; off = ww; }
        else if (ww < 8)  { Wm = W_fi; bm = b_fi; nc = 2; c = ww - 6; off = ww; }
        else if (ww < 10) { Wm = W_he; bm = b_he; nc = 2; c = ww - 8; off = ww; }
        else if (ww == 10){ Wm = W_ra; bm = b_ra; nc = 1; c = 0;      off = 10; }
        else              { Wm = W_rb; bm = b_rb; nc = 1; c = 0;      off = 11; }
        float acc = bm[c];
        for (int i = 0; i < 128; ++i) acc = fmaf(s_x[r][i], Wm[i * nc + c], acc);
        if (ww >= 10) acc = fmaxf(acc, 0.0f) + log1pf(__expf(-fabsf(acc))) + 1.0f;
        out[(size_t)(r0 + r) * 268 + off] = acc;
    }
}

extern "C" void kernel_launch(void* const* d_in, const int* in_sizes, int n_in,
                              void* d_out, int out_size, void* d_ws, size_t ws_size,
                              hipStream_t stream) {
    (void)n_in; (void)out_size; (void)d_ws; (void)ws_size;
    const float* self_feat = (const float*)d_in[0];
    const float* entities  = (const float*)d_in[1];
    const void*  mask      = d_in[2];
    const float* hx  = (const float*)d_in[3];
    const float* cx  = (const float*)d_in[4];
    const float* W_se = (const float*)d_in[5],  *b_se = (const float*)d_in[6];
    const float* W_ee = (const float*)d_in[7],  *b_ee = (const float*)d_in[8];
    const float* W_q  = (const float*)d_in[9],  *b_q  = (const float*)d_in[10];
    const float* W_k  = (const float*)d_in[11], *b_k  = (const float*)d_in[12];
    const float* W_v  = (const float*)d_in[13], *b_v  = (const float*)d_in[14];
    const float* W_p1 = (const float*)d_in[15], *b_p1 = (const float*)d_in[16];
    const float* W_p2 = (const float*)d_in[17], *b_p2 = (const float*)d_in[18];
    const float* W_ih = (const float*)d_in[19], *b_ih = (const float*)d_in[20];
    const float* W_hh = (const float*)d_in[21], *b_hh = (const float*)d_in[22];
    const float* W_a  = (const float*)d_in[23], *b_a  = (const float*)d_in[24];
    const float* W_mx = (const float*)d_in[25], *b_mx = (const float*)d_in[26];
    const float* W_my = (const float*)d_in[27], *b_my = (const float*)d_in[28];
    const float* W_fi = (const float*)d_in[29], *b_fi = (const float*)d_in[30];
    const float* W_he = (const float*)d_in[31], *b_he = (const float*)d_in[32];
    const float* W_ra = (const float*)d_in[33], *b_ra = (const float*)d_in[34];
    const float* W_rb = (const float*)d_in[35], *b_rb = (const float*)d_in[36];
    float* out = (float*)d_out;

    const int B = in_sizes[0] / 24;   // 8192

    ka_attention_v5<<<B / 4, 256, 0, stream>>>(self_feat, entities, mask,
        W_se, b_se, W_ee, b_ee, W_q, b_q, W_k, b_k, W_v, b_v, out);
    kb_lstm_heads<<<B / BB, 512, 0, stream>>>(hx, cx,
        W_p1, b_p1, W_p2, b_p2, W_ih, b_ih, W_hh, b_hh, W_a, b_a,
        W_mx, b_mx, W_my, b_my, W_fi, b_fi, W_he, b_he, W_ra, b_ra, W_rb, b_rb, out);
}

// Round 10
// 159.042 us; speedup vs baseline: 5.9595x; 1.0011x over previous
//
#include <hip/hip_runtime.h>
#include <math.h>

#define BB 16

typedef __attribute__((ext_vector_type(8))) unsigned short ushort8;

__device__ __forceinline__ float sigf(float x) { return 1.0f / (1.0f + __expf(-x)); }

__device__ __forceinline__ float bf2f(unsigned short s) {
    return __uint_as_float(((unsigned int)s) << 16);
}
__device__ __forceinline__ unsigned short f2bf(float f) {
    return (unsigned short)((__float_as_uint(f) + 0x8000u) >> 16);
}

#define WAVE_WAIT() asm volatile("s_waitcnt lgkmcnt(0)" ::: "memory")

// ---------------- Kernel A v5: one WAVE per row, zero block barriers in the
// per-row path. Flash over 2 passes of 64 entities; lane=entity for encode+
// scores (W_ee uniform from LDS), bf16 tile only for the ctx transpose.
__global__ __launch_bounds__(256) void ka_attention_v5(
    const float* __restrict__ self_feat,   // (B,24)
    const float* __restrict__ entities,    // (B,128,12)
    const void*  __restrict__ mask_raw,    // (B,128) int32 or uint8
    const float* __restrict__ W_se, const float* __restrict__ b_se,
    const float* __restrict__ W_ee, const float* __restrict__ b_ee,
    const float* __restrict__ W_q,  const float* __restrict__ b_q,
    const float* __restrict__ W_k,  const float* __restrict__ b_k,
    const float* __restrict__ W_v,  const float* __restrict__ b_v,
    float* out)                            // (B,268)
{
    const int t = threadIdx.x;
    const int l = t & 63;
    const int w = __builtin_amdgcn_readfirstlane(t >> 6);   // wave id = row within block
    const int b = blockIdx.x * 4 + w;

    __shared__ float s_wee[768];                              // 3 KB, block-shared
    __shared__ __align__(16) unsigned short s_tile[4][64][64];// 32 KB, wave-private
    __shared__ __align__(16) float s_qk[4][64][4];            // qkh [i][h]
    __shared__ __align__(16) float s_p[4][64][4];             // tile weights [n][h]
    __shared__ __align__(16) float s_ctx[4][64][4];           // ctx [i][h]
    __shared__ float s_emb[4][64];
    __shared__ float s_q[4][64];

    // ---- stage W_ee (global layout [i][d]) cooperatively
    s_wee[t]       = W_ee[t];
    s_wee[t + 256] = W_ee[t + 256];
    s_wee[t + 512] = W_ee[t + 512];

    // ---- mask dtype probe (uniform scalar loads)
    bool mask_is_int = true;
    {
        const unsigned int* mw = (const unsigned int*)mask_raw;
        #pragma unroll
        for (int w0 = 0; w0 < 64; ++w0) mask_is_int = mask_is_int && (mw[w0] <= 1u);
    }

    __syncthreads();   // the ONLY block barrier: s_wee ready

    // ================= per-wave (one row) from here =================

    // ---- self_embed (lane = dim)
    float emb = b_se[l];
    {
        const float* sfp = self_feat + (size_t)b * 24;
        #pragma unroll
        for (int i = 0; i < 24; ++i) emb = fmaf(sfp[i], W_se[i * 64 + l], emb);
        emb = fmaxf(emb, 0.0f);
    }
    s_emb[w][l] = emb;
    WAVE_WAIT();

    // ---- q (lane = dim): emb uniform from LDS, W_q coalesced
    float qv = b_q[l];
    #pragma unroll
    for (int i4 = 0; i4 < 16; ++i4) {
        const float4 ev = *(const float4*)&s_emb[w][i4 * 4];
        qv = fmaf(ev.x, W_q[(i4 * 4 + 0) * 64 + l], qv);
        qv = fmaf(ev.y, W_q[(i4 * 4 + 1) * 64 + l], qv);
        qv = fmaf(ev.z, W_q[(i4 * 4 + 2) * 64 + l], qv);
        qv = fmaf(ev.w, W_q[(i4 * 4 + 3) * 64 + l], qv);
    }
    s_q[w][l] = qv;

    // ---- qb[h] = sum_{d in head h} q[d]*b_k[d], broadcast to all lanes
    float vb = qv * b_k[l];
    vb += __shfl_xor(vb, 1); vb += __shfl_xor(vb, 2);
    vb += __shfl_xor(vb, 4); vb += __shfl_xor(vb, 8);
    const float qb0 = __shfl(vb, 0),  qb1 = __shfl(vb, 16);
    const float qb2 = __shfl(vb, 32), qb3 = __shfl(vb, 48);
    WAVE_WAIT();

    // ---- qkh[i][h]: lane (i=l>>2, h=l&3) owns a contiguous 64B quarter-row of
    // W_k -> fully coalesced. 4 i-groups of 16.
    {
        const int hh = l & 3;
        #pragma unroll
        for (int g = 0; g < 4; ++g) {
            const int i = g * 16 + (l >> 2);
            const float* wk = W_k + i * 64 + hh * 16;
            float acc = 0.0f;
            #pragma unroll
            for (int j4 = 0; j4 < 4; ++j4) {
                const float4 kv = *(const float4*)(wk + j4 * 4);
                const float4 qq = *(const float4*)&s_q[w][hh * 16 + j4 * 4];
                acc = fmaf(kv.x, qq.x, acc); acc = fmaf(kv.y, qq.y, acc);
                acc = fmaf(kv.z, qq.z, acc); acc = fmaf(kv.w, qq.w, acc);
            }
            s_qk[w][i][hh] = acc;
        }
    }

    // ---- flash state (replicated across lanes) + ctx accumulators (lane = dim)
    float m0 = -1e30f, m1 = -1e30f, m2 = -1e30f, m3 = -1e30f;
    float ll0 = 0.f, ll1 = 0.f, ll2 = 0.f, ll3 = 0.f;
    float ctx0 = 0.f, ctx1 = 0.f, ctx2 = 0.f, ctx3 = 0.f;

    const float4* beev = (const float4*)b_ee;

    #pragma unroll 1
    for (int pass = 0; pass < 2; ++pass) {
        const int n = pass * 64 + l;     // lane = entity

        bool msk;
        if (mask_is_int) msk = ((const int*)mask_raw)[(size_t)b * 128 + n] != 0;
        else             msk = ((const unsigned char*)mask_raw)[(size_t)b * 128 + n] != 0;

        const float* ep = entities + (size_t)b * 1536 + n * 12;
        const float4 e0 = *(const float4*)ep;
        const float4 e1 = *(const float4*)(ep + 4);
        const float4 e2 = *(const float4*)(ep + 8);

        // -- encode own entity: ee[d] d=0..63 in 16 float4 accumulators
        float4 ee4[16];
        #pragma unroll
        for (int d4 = 0; d4 < 16; ++d4) ee4[d4] = beev[d4];
        #define ENC(EIV, ROW)                                                  \
            { const float eiv_ = (EIV);                                        \
              _Pragma("unroll")                                                \
              for (int d4 = 0; d4 < 16; ++d4) {                                \
                  const float4 wv = *(const float4*)&s_wee[(ROW) * 64 + d4*4]; \
                  ee4[d4].x = fmaf(eiv_, wv.x, ee4[d4].x);                     \
                  ee4[d4].y = fmaf(eiv_, wv.y, ee4[d4].y);                     \
                  ee4[d4].z = fmaf(eiv_, wv.z, ee4[d4].z);                     \
                  ee4[d4].w = fmaf(eiv_, wv.w, ee4[d4].w); } }
        ENC(e0.x, 0)  ENC(e0.y, 1)  ENC(e0.z, 2)  ENC(e0.w, 3)
        ENC(e1.x, 4)  ENC(e1.y, 5)  ENC(e1.z, 6)  ENC(e1.w, 7)
        ENC(e2.x, 8)  ENC(e2.y, 9)  ENC(e2.z, 10) ENC(e2.w, 11)
        #undef ENC

        // -- relu + pack + write own tile row (XOR swizzle on 16B col-groups)
        #pragma unroll
        for (int c8 = 0; c8 < 8; ++c8) {
            const float4 a = ee4[c8 * 2], c = ee4[c8 * 2 + 1];
            ushort8 sv;
            sv[0] = f2bf(fmaxf(a.x, 0.f)); sv[1] = f2bf(fmaxf(a.y, 0.f));
            sv[2] = f2bf(fmaxf(a.z, 0.f)); sv[3] = f2bf(fmaxf(a.w, 0.f));
            sv[4] = f2bf(fmaxf(c.x, 0.f)); sv[5] = f2bf(fmaxf(c.y, 0.f));
            sv[6] = f2bf(fmaxf(c.z, 0.f)); sv[7] = f2bf(fmaxf(c.w, 0.f));
            *(ushort8*)&s_tile[w][l][(c8 ^ (l & 7)) << 3] = sv;
        }
        WAVE_WAIT();   // tile row + s_qk visible to own wave

        // -- scores for own entity (read row back in bf16; frees ee4 regs)
        float sc0 = 0.f, sc1 = 0.f, sc2 = 0.f, sc3 = 0.f;
        #pragma unroll
        for (int c8 = 0; c8 < 8; ++c8) {
            const ushort8 evv = *(const ushort8*)&s_tile[w][l][(c8 ^ (l & 7)) << 3];
            #pragma unroll
            for (int k = 0; k < 8; ++k) {
                const float e = bf2f(evv[k]);
                const float4 qk = *(const float4*)&s_qk[w][c8 * 8 + k][0];
                sc0 = fmaf(e, qk.x, sc0); sc1 = fmaf(e, qk.y, sc1);
                sc2 = fmaf(e, qk.z, sc2); sc3 = fmaf(e, qk.w, sc3);
            }
        }
        sc0 = msk ? (sc0 + qb0) * 0.25f : -1e30f;
        sc1 = msk ? (sc1 + qb1) * 0.25f : -1e30f;
        sc2 = msk ? (sc2 + qb2) * 0.25f : -1e30f;
        sc3 = msk ? (sc3 + qb3) * 0.25f : -1e30f;

        // -- flash update (full-wave reductions -> state replicated)
        float t0 = sc0, t1 = sc1, t2 = sc2, t3 = sc3;
        #pragma unroll
        for (int d = 1; d < 64; d <<= 1) {
            t0 = fmaxf(t0, __shfl_xor(t0, d)); t1 = fmaxf(t1, __shfl_xor(t1, d));
            t2 = fmaxf(t2, __shfl_xor(t2, d)); t3 = fmaxf(t3, __shfl_xor(t3, d));
        }
        const float mn0 = fmaxf(m0, t0), mn1 = fmaxf(m1, t1);
        const float mn2 = fmaxf(m2, t2), mn3 = fmaxf(m3, t3);
        const float sl0 = __expf(m0 - mn0), sl1 = __expf(m1 - mn1);
        const float sl2 = __expf(m2 - mn2), sl3 = __expf(m3 - mn3);
        const float p0 = msk ? __expf(sc0 - mn0) : 0.0f;
        const float p1 = msk ? __expf(sc1 - mn1) : 0.0f;
        const float p2 = msk ? __expf(sc2 - mn2) : 0.0f;
        const float p3 = msk ? __expf(sc3 - mn3) : 0.0f;
        float ps0 = p0, ps1 = p1, ps2 = p2, ps3 = p3;
        #pragma unroll
        for (int d = 1; d < 64; d <<= 1) {
            ps0 += __shfl_xor(ps0, d); ps1 += __shfl_xor(ps1, d);
            ps2 += __shfl_xor(ps2, d); ps3 += __shfl_xor(ps3, d);
        }
        ll0 = ll0 * sl0 + ps0; ll1 = ll1 * sl1 + ps1;
        ll2 = ll2 * sl2 + ps2; ll3 = ll3 * sl3 + ps3;
        m0 = mn0; m1 = mn1; m2 = mn2; m3 = mn3;

        { float4 pv; pv.x = p0; pv.y = p1; pv.z = p2; pv.w = p3;
          *(float4*)&s_p[w][l][0] = pv; }
        WAVE_WAIT();   // p visible

        // -- ctx accumulate (lane = dim l): p uniform, ee from tile column
        ctx0 *= sl0; ctx1 *= sl1; ctx2 *= sl2; ctx3 *= sl3;
        const int cb = (l >> 3) << 3, lo = l & 7;
        #pragma unroll 8
        for (int j = 0; j < 64; ++j) {
            const float4 pj = *(const float4*)&s_p[w][j][0];
            const float e = bf2f(s_tile[w][j][(cb ^ ((j & 7) << 3)) + lo]);
            ctx0 = fmaf(pj.x, e, ctx0); ctx1 = fmaf(pj.y, e, ctx1);
            ctx2 = fmaf(pj.z, e, ctx2); ctx3 = fmaf(pj.w, e, ctx3);
        }
        WAVE_WAIT();   // ctx reads done before next pass overwrites tile
    }

    // ---- finalize: normalize ctx, publish, project with W_v (lane = out dim)
    {
        const float i0 = ll0 > 0.f ? 1.f / ll0 : 0.f;
        const float i1 = ll1 > 0.f ? 1.f / ll1 : 0.f;
        const float i2 = ll2 > 0.f ? 1.f / ll2 : 0.f;
        const float i3 = ll3 > 0.f ? 1.f / ll3 : 0.f;
        float4 cv; cv.x = ctx0 * i0; cv.y = ctx1 * i1; cv.z = ctx2 * i2; cv.w = ctx3 * i3;
        *(float4*)&s_ctx[w][l][0] = cv;
    }
    WAVE_WAIT();
    {
        const int h = l >> 4;
        float ao = b_v[l];
        #pragma unroll 8
        for (int i = 0; i < 64; ++i) ao = fmaf(s_ctx[w][i][h], W_v[i * 64 + l], ao);
        out[(size_t)b * 268 + 12 + l] = emb;   // combined[0:64)
        out[(size_t)b * 268 + 76 + l] = ao;    // combined[64:128)
    }
}

// 128x128 GEMV over 16 rows staged in LDS; 512 threads: 4 row-groups x 128 cols.
__device__ __forceinline__ void gemv128_512(const float (*s_in)[128], float (*s_out)[128],
                                            const float* __restrict__ W,
                                            const float* __restrict__ bvec,
                                            int t, bool relu_)
{
    const int oo = t & 127;
    const int rb = (t >> 7) * 4;
    const float bv = bvec[oo];
    float acc[4];
    #pragma unroll
    for (int r = 0; r < 4; ++r) acc[r] = bv;
    #pragma unroll 4
    for (int i = 0; i < 128; ++i) {
        const float wt = W[i * 128 + oo];
        #pragma unroll
        for (int r = 0; r < 4; ++r) acc[r] = fmaf(s_in[rb + r][i], wt, acc[r]);
    }
    #pragma unroll
    for (int r = 0; r < 4; ++r) s_out[rb + r][oo] = relu_ ? fmaxf(acc[r], 0.0f) : acc[r];
}

// ---------------- Kernel B: MLP + LSTM + actor heads (16 rows, 512 threads)
__global__ __launch_bounds__(512) void kb_lstm_heads(
    const float* __restrict__ hx, const float* __restrict__ cx,
    const float* __restrict__ W_p1, const float* __restrict__ b_p1,
    const float* __restrict__ W_p2, const float* __restrict__ b_p2,
    const float* __restrict__ W_ih, const float* __restrict__ b_ih,
    const float* __restrict__ W_hh, const float* __restrict__ b_hh,
    const float* __restrict__ W_a,  const float* __restrict__ b_a,
    const float* __restrict__ W_mx, const float* __restrict__ b_mx,
    const float* __restrict__ W_my, const float* __restrict__ b_my,
    const float* __restrict__ W_fi, const float* __restrict__ b_fi,
    const float* __restrict__ W_he, const float* __restrict__ b_he,
    const float* __restrict__ W_ra, const float* __restrict__ b_ra,
    const float* __restrict__ W_rb, const float* __restrict__ b_rb,
    float* out)   // aliases the combined staging area — no __restrict__
{
    const int t = threadIdx.x;   // 0..511
    const int r0 = blockIdx.x * BB;

    __shared__ float s_x[BB][128];   // combined -> reactive -> h
    __shared__ float s_y[BB][128];   // r1 -> features
    __shared__ float s_hx[BB][128];
    __shared__ float s_g[BB][512];   // gates

    for (int idx = t; idx < BB * 128; idx += 512) {
        const int r = idx >> 7, j = idx & 127;
        s_x[r][j]  = out[(size_t)(r0 + r) * 268 + 12 + j];
        s_hx[r][j] = hx[(size_t)(r0 + r) * 128 + j];
    }
    __syncthreads();

    gemv128_512(s_x, s_y, W_p1, b_p1, t, true);    // r1
    __syncthreads();
    gemv128_512(s_y, s_x, W_p2, b_p2, t, true);    // reactive
    __syncthreads();

    // ---- LSTM gates: thread t owns output col t (0..511) across all 16 rows
    {
        float acc[16];
        const float bs = b_ih[t] + b_hh[t];
        #pragma unroll
        for (int r = 0; r < 16; ++r) acc[r] = bs;
        #pragma unroll 4
        for (int i = 0; i < 128; ++i) {
            const float w1 = W_ih[i * 512 + t];
            #pragma unroll
            for (int r = 0; r < 16; ++r) acc[r] = fmaf(s_x[r][i], w1, acc[r]);
        }
        #pragma unroll 4
        for (int i = 0; i < 128; ++i) {
            const float w1 = W_hh[i * 512 + t];
            #pragma unroll
            for (int r = 0; r < 16; ++r) acc[r] = fmaf(s_hx[r][i], w1, acc[r]);
        }
        #pragma unroll
        for (int r = 0; r < 16; ++r) s_g[r][t] = acc[r];
    }
    __syncthreads();

    // ---- LSTM elementwise (gate order i,f,g,o)
    for (int idx = t; idx < BB * 128; idx += 512) {
        const int r = idx >> 7, j = idx & 127;
        const float ig = s_g[r][j];
        const float fg = s_g[r][j + 128];
        const float gg = s_g[r][j + 256];
        const float og = s_g[r][j + 384];
        const float c_old = cx[(size_t)(r0 + r) * 128 + j];
        const float c_new = sigf(fg) * c_old + sigf(ig) * tanhf(gg);
        const float h_new = sigf(og) * tanhf(c_new);
        out[(size_t)(r0 + r) * 268 + 12 + j]  = h_new;
        out[(size_t)(r0 + r) * 268 + 140 + j] = c_new;
        s_y[r][j] = s_x[r][j] + h_new;   // features = reactive + hx_new
    }
    __syncthreads();

    gemv128_512(s_y, s_x, W_a, b_a, t, true);      // h
    __syncthreads();

    // ---- small heads: 12 scalar outputs per row
    if (t < BB * 12) {
        const int r = t / 12, ww = t % 12;
        const float* Wm; const float* bm; int nc, c, off;
        if (ww < 3)       { Wm = W_mx; bm = b_mx; nc = 3; c = ww;     off = ww; }
        else if (ww < 6)  { Wm = W_my; bm = b_my; nc = 3; c = ww - 3; off = ww; }
        else if (ww < 8)  { Wm = W_fi; bm = b_fi; nc = 2; c = ww - 6; off = ww; }
        else if (ww < 10) { Wm = W_he; bm = b_he; nc = 2; c = ww - 8; off = ww; }
        else if (ww == 10){ Wm = W_ra; bm = b_ra; nc = 1; c = 0;      off = 10; }
        else              { Wm = W_rb; bm = b_rb; nc = 1; c = 0;      off = 11; }
        float acc = bm[c];
        for (int i = 0; i < 128; ++i) acc = fmaf(s_x[r][i], Wm[i * nc + c], acc);
        if (ww >= 10) acc = fmaxf(acc, 0.0f) + log1pf(__expf(-fabsf(acc))) + 1.0f;
        out[(size_t)(r0 + r) * 268 + off] = acc;
    }
}

extern "C" void kernel_launch(void* const* d_in, const int* in_sizes, int n_in,
                              void* d_out, int out_size, void* d_ws, size_t ws_size,
                              hipStream_t stream) {
    (void)n_in; (void)out_size; (void)d_ws; (void)ws_size;
    const float* self_feat = (const float*)d_in[0];
    const float* entities  = (const float*)d_in[1];
    const void*  mask      = d_in[2];
    const float* hx  = (const float*)d_in[3];
    const float* cx  = (const float*)d_in[4];
    const float* W_se = (const float*)d_in[5],  *b_se = (const float*)d_in[6];
    const float* W_ee = (const float*)d_in[7],  *b_ee = (const float*)d_in[8];
    const float* W_q  = (const float*)d_in[9],  *b_q  = (const float*)d_in[10];
    const float* W_k  = (const float*)d_in[11], *b_k  = (const float*)d_in[12];
    const float* W_v  = (const float*)d_in[13], *b_v  = (const float*)d_in[14];
    const float* W_p1 = (const float*)d_in[15], *b_p1 = (const float*)d_in[16];
    const float* W_p2 = (const float*)d_in[17], *b_p2 = (const float*)d_in[18];
    const float* W_ih = (const float*)d_in[19], *b_ih = (const float*)d_in[20];
    const float* W_hh = (const float*)d_in[21], *b_hh = (const float*)d_in[22];
    const float* W_a  = (const float*)d_in[23], *b_a  = (const float*)d_in[24];
    const float* W_mx = (const float*)d_in[25], *b_mx = (const float*)d_in[26];
    const float* W_my = (const float*)d_in[27], *b_my = (const float*)d_in[28];
    const float* W_fi = (const float*)d_in[29], *b_fi = (const float*)d_in[30];
    const float* W_he = (const float*)d_in[31], *b_he = (const float*)d_in[32];
    const float* W_ra = (const float*)d_in[33], *b_ra = (const float*)d_in[34];
    const float* W_rb = (const float*)d_in[35], *b_rb = (const float*)d_in[36];
    float* out = (float*)d_out;

    const int B = in_sizes[0] / 24;   // 8192

    ka_attention_v5<<<B / 4, 256, 0, stream>>>(self_feat, entities, mask,
        W_se, b_se, W_ee, b_ee, W_q, b_q, W_k, b_k, W_v, b_v, out);
    kb_lstm_heads<<<B / BB, 512, 0, stream>>>(hx, cx,
        W_p1, b_p1, W_p2, b_p2, W_ih, b_ih, W_hh, b_hh, W_a, b_a,
        W_mx, b_mx, W_my, b_my, W_fi, b_fi, W_he, b_he, W_ra, b_ra, W_rb, b_rb, out);
}

// Round 11
// 113.610 us; speedup vs baseline: 8.3427x; 1.3999x over previous
//
#include <hip/hip_runtime.h>
#include <math.h>

#define BB 16

typedef __attribute__((ext_vector_type(8))) unsigned short ushort8;
typedef __attribute__((ext_vector_type(8))) short short8v;
typedef __attribute__((ext_vector_type(4))) float f32x4;

__device__ __forceinline__ float sigf(float x) { return 1.0f / (1.0f + __expf(-x)); }

__device__ __forceinline__ float bf2f(unsigned short s) {
    return __uint_as_float(((unsigned int)s) << 16);
}
__device__ __forceinline__ unsigned short f2bf(float f) {
    return (unsigned short)((__float_as_uint(f) + 0x8000u) >> 16);
}

#define WAVE_WAIT() asm volatile("s_waitcnt lgkmcnt(0)" ::: "memory")

// ================= Kernel A v5 (unchanged): one WAVE per row =================
__global__ __launch_bounds__(256) void ka_attention_v5(
    const float* __restrict__ self_feat,
    const float* __restrict__ entities,
    const void*  __restrict__ mask_raw,
    const float* __restrict__ W_se, const float* __restrict__ b_se,
    const float* __restrict__ W_ee, const float* __restrict__ b_ee,
    const float* __restrict__ W_q,  const float* __restrict__ b_q,
    const float* __restrict__ W_k,  const float* __restrict__ b_k,
    const float* __restrict__ W_v,  const float* __restrict__ b_v,
    float* out)
{
    const int t = threadIdx.x;
    const int l = t & 63;
    const int w = __builtin_amdgcn_readfirstlane(t >> 6);
    const int b = blockIdx.x * 4 + w;

    __shared__ float s_wee[768];
    __shared__ __align__(16) unsigned short s_tile[4][64][64];
    __shared__ __align__(16) float s_qk[4][64][4];
    __shared__ __align__(16) float s_p[4][64][4];
    __shared__ __align__(16) float s_ctx[4][64][4];
    __shared__ float s_emb[4][64];
    __shared__ float s_q[4][64];

    s_wee[t]       = W_ee[t];
    s_wee[t + 256] = W_ee[t + 256];
    s_wee[t + 512] = W_ee[t + 512];

    bool mask_is_int = true;
    {
        const unsigned int* mw = (const unsigned int*)mask_raw;
        #pragma unroll
        for (int w0 = 0; w0 < 64; ++w0) mask_is_int = mask_is_int && (mw[w0] <= 1u);
    }

    __syncthreads();

    float emb = b_se[l];
    {
        const float* sfp = self_feat + (size_t)b * 24;
        #pragma unroll
        for (int i = 0; i < 24; ++i) emb = fmaf(sfp[i], W_se[i * 64 + l], emb);
        emb = fmaxf(emb, 0.0f);
    }
    s_emb[w][l] = emb;
    WAVE_WAIT();

    float qv = b_q[l];
    #pragma unroll
    for (int i4 = 0; i4 < 16; ++i4) {
        const float4 ev = *(const float4*)&s_emb[w][i4 * 4];
        qv = fmaf(ev.x, W_q[(i4 * 4 + 0) * 64 + l], qv);
        qv = fmaf(ev.y, W_q[(i4 * 4 + 1) * 64 + l], qv);
        qv = fmaf(ev.z, W_q[(i4 * 4 + 2) * 64 + l], qv);
        qv = fmaf(ev.w, W_q[(i4 * 4 + 3) * 64 + l], qv);
    }
    s_q[w][l] = qv;

    float vb = qv * b_k[l];
    vb += __shfl_xor(vb, 1); vb += __shfl_xor(vb, 2);
    vb += __shfl_xor(vb, 4); vb += __shfl_xor(vb, 8);
    const float qb0 = __shfl(vb, 0),  qb1 = __shfl(vb, 16);
    const float qb2 = __shfl(vb, 32), qb3 = __shfl(vb, 48);
    WAVE_WAIT();

    {
        const int hh = l & 3;
        #pragma unroll
        for (int g = 0; g < 4; ++g) {
            const int i = g * 16 + (l >> 2);
            const float* wk = W_k + i * 64 + hh * 16;
            float acc = 0.0f;
            #pragma unroll
            for (int j4 = 0; j4 < 4; ++j4) {
                const float4 kv = *(const float4*)(wk + j4 * 4);
                const float4 qq = *(const float4*)&s_q[w][hh * 16 + j4 * 4];
                acc = fmaf(kv.x, qq.x, acc); acc = fmaf(kv.y, qq.y, acc);
                acc = fmaf(kv.z, qq.z, acc); acc = fmaf(kv.w, qq.w, acc);
            }
            s_qk[w][i][hh] = acc;
        }
    }

    float m0 = -1e30f, m1 = -1e30f, m2 = -1e30f, m3 = -1e30f;
    float ll0 = 0.f, ll1 = 0.f, ll2 = 0.f, ll3 = 0.f;
    float ctx0 = 0.f, ctx1 = 0.f, ctx2 = 0.f, ctx3 = 0.f;

    const float4* beev = (const float4*)b_ee;

    #pragma unroll 1
    for (int pass = 0; pass < 2; ++pass) {
        const int n = pass * 64 + l;

        bool msk;
        if (mask_is_int) msk = ((const int*)mask_raw)[(size_t)b * 128 + n] != 0;
        else             msk = ((const unsigned char*)mask_raw)[(size_t)b * 128 + n] != 0;

        const float* ep = entities + (size_t)b * 1536 + n * 12;
        const float4 e0 = *(const float4*)ep;
        const float4 e1 = *(const float4*)(ep + 4);
        const float4 e2 = *(const float4*)(ep + 8);

        float4 ee4[16];
        #pragma unroll
        for (int d4 = 0; d4 < 16; ++d4) ee4[d4] = beev[d4];
        #define ENC(EIV, ROW)                                                  \
            { const float eiv_ = (EIV);                                        \
              _Pragma("unroll")                                                \
              for (int d4 = 0; d4 < 16; ++d4) {                                \
                  const float4 wv = *(const float4*)&s_wee[(ROW) * 64 + d4*4]; \
                  ee4[d4].x = fmaf(eiv_, wv.x, ee4[d4].x);                     \
                  ee4[d4].y = fmaf(eiv_, wv.y, ee4[d4].y);                     \
                  ee4[d4].z = fmaf(eiv_, wv.z, ee4[d4].z);                     \
                  ee4[d4].w = fmaf(eiv_, wv.w, ee4[d4].w); } }
        ENC(e0.x, 0)  ENC(e0.y, 1)  ENC(e0.z, 2)  ENC(e0.w, 3)
        ENC(e1.x, 4)  ENC(e1.y, 5)  ENC(e1.z, 6)  ENC(e1.w, 7)
        ENC(e2.x, 8)  ENC(e2.y, 9)  ENC(e2.z, 10) ENC(e2.w, 11)
        #undef ENC

        #pragma unroll
        for (int c8 = 0; c8 < 8; ++c8) {
            const float4 a = ee4[c8 * 2], c = ee4[c8 * 2 + 1];
            ushort8 sv;
            sv[0] = f2bf(fmaxf(a.x, 0.f)); sv[1] = f2bf(fmaxf(a.y, 0.f));
            sv[2] = f2bf(fmaxf(a.z, 0.f)); sv[3] = f2bf(fmaxf(a.w, 0.f));
            sv[4] = f2bf(fmaxf(c.x, 0.f)); sv[5] = f2bf(fmaxf(c.y, 0.f));
            sv[6] = f2bf(fmaxf(c.z, 0.f)); sv[7] = f2bf(fmaxf(c.w, 0.f));
            *(ushort8*)&s_tile[w][l][(c8 ^ (l & 7)) << 3] = sv;
        }
        WAVE_WAIT();

        float sc0 = 0.f, sc1 = 0.f, sc2 = 0.f, sc3 = 0.f;
        #pragma unroll
        for (int c8 = 0; c8 < 8; ++c8) {
            const ushort8 evv = *(const ushort8*)&s_tile[w][l][(c8 ^ (l & 7)) << 3];
            #pragma unroll
            for (int k = 0; k < 8; ++k) {
                const float e = bf2f(evv[k]);
                const float4 qk = *(const float4*)&s_qk[w][c8 * 8 + k][0];
                sc0 = fmaf(e, qk.x, sc0); sc1 = fmaf(e, qk.y, sc1);
                sc2 = fmaf(e, qk.z, sc2); sc3 = fmaf(e, qk.w, sc3);
            }
        }
        sc0 = msk ? (sc0 + qb0) * 0.25f : -1e30f;
        sc1 = msk ? (sc1 + qb1) * 0.25f : -1e30f;
        sc2 = msk ? (sc2 + qb2) * 0.25f : -1e30f;
        sc3 = msk ? (sc3 + qb3) * 0.25f : -1e30f;

        float t0 = sc0, t1 = sc1, t2 = sc2, t3 = sc3;
        #pragma unroll
        for (int d = 1; d < 64; d <<= 1) {
            t0 = fmaxf(t0, __shfl_xor(t0, d)); t1 = fmaxf(t1, __shfl_xor(t1, d));
            t2 = fmaxf(t2, __shfl_xor(t2, d)); t3 = fmaxf(t3, __shfl_xor(t3, d));
        }
        const float mn0 = fmaxf(m0, t0), mn1 = fmaxf(m1, t1);
        const float mn2 = fmaxf(m2, t2), mn3 = fmaxf(m3, t3);
        const float sl0 = __expf(m0 - mn0), sl1 = __expf(m1 - mn1);
        const float sl2 = __expf(m2 - mn2), sl3 = __expf(m3 - mn3);
        const float p0 = msk ? __expf(sc0 - mn0) : 0.0f;
        const float p1 = msk ? __expf(sc1 - mn1) : 0.0f;
        const float p2 = msk ? __expf(sc2 - mn2) : 0.0f;
        const float p3 = msk ? __expf(sc3 - mn3) : 0.0f;
        float ps0 = p0, ps1 = p1, ps2 = p2, ps3 = p3;
        #pragma unroll
        for (int d = 1; d < 64; d <<= 1) {
            ps0 += __shfl_xor(ps0, d); ps1 += __shfl_xor(ps1, d);
            ps2 += __shfl_xor(ps2, d); ps3 += __shfl_xor(ps3, d);
        }
        ll0 = ll0 * sl0 + ps0; ll1 = ll1 * sl1 + ps1;
        ll2 = ll2 * sl2 + ps2; ll3 = ll3 * sl3 + ps3;
        m0 = mn0; m1 = mn1; m2 = mn2; m3 = mn3;

        { float4 pv; pv.x = p0; pv.y = p1; pv.z = p2; pv.w = p3;
          *(float4*)&s_p[w][l][0] = pv; }
        WAVE_WAIT();

        ctx0 *= sl0; ctx1 *= sl1; ctx2 *= sl2; ctx3 *= sl3;
        const int cb = (l >> 3) << 3, lo = l & 7;
        #pragma unroll 8
        for (int j = 0; j < 64; ++j) {
            const float4 pj = *(const float4*)&s_p[w][j][0];
            const float e = bf2f(s_tile[w][j][(cb ^ ((j & 7) << 3)) + lo]);
            ctx0 = fmaf(pj.x, e, ctx0); ctx1 = fmaf(pj.y, e, ctx1);
            ctx2 = fmaf(pj.z, e, ctx2); ctx3 = fmaf(pj.w, e, ctx3);
        }
        WAVE_WAIT();
    }

    {
        const float i0 = ll0 > 0.f ? 1.f / ll0 : 0.f;
        const float i1 = ll1 > 0.f ? 1.f / ll1 : 0.f;
        const float i2 = ll2 > 0.f ? 1.f / ll2 : 0.f;
        const float i3 = ll3 > 0.f ? 1.f / ll3 : 0.f;
        float4 cv; cv.x = ctx0 * i0; cv.y = ctx1 * i1; cv.z = ctx2 * i2; cv.w = ctx3 * i3;
        *(float4*)&s_ctx[w][l][0] = cv;
    }
    WAVE_WAIT();
    {
        const int h = l >> 4;
        float ao = b_v[l];
        #pragma unroll 8
        for (int i = 0; i < 64; ++i) ao = fmaf(s_ctx[w][i][h], W_v[i * 64 + l], ao);
        out[(size_t)b * 268 + 12 + l] = emb;
        out[(size_t)b * 268 + 76 + l] = ao;
    }
}

// ================= weight pack: fp32 -> bf16 in MFMA B-fragment order =======
// B-frag for mfma_f32_16x16x32_bf16: lane = (kgrp<<4)|n_l holds B[k][n] for
// n = ntile*16 + n_l, k = ktile*32 + kgrp*8 + j (j=0..7, one b128 per lane).
// Packed elem index: ((ntile*KT + ktile)*64 + lane)*8 + j.
#define PK_GATES 0          /* [W_ih;W_hh] as 256x512, KT=8  -> 131072 elems */
#define PK_P1    131072     /* 128x128, KT=4 -> 16384 */
#define PK_P2    147456
#define PK_WA    163840
#define PK_TOTAL 180224     /* ushorts; 360448 bytes */

__global__ __launch_bounds__(256) void pack_weights(
    const float* __restrict__ W_ih, const float* __restrict__ W_hh,
    const float* __restrict__ W_p1, const float* __restrict__ W_p2,
    const float* __restrict__ W_a,  unsigned short* __restrict__ dst)
{
    const int tid = blockIdx.x * 256 + threadIdx.x;
    const float* W; int N, KT, base, k_off, idx;
    if (tid < 65536)       { W = W_ih; N = 512; KT = 8; base = PK_GATES; k_off = 0;   idx = tid; }
    else if (tid < 131072) { W = W_hh; N = 512; KT = 8; base = PK_GATES; k_off = 128; idx = tid - 65536; }
    else if (tid < 147456) { W = W_p1; N = 128; KT = 4; base = PK_P1;    k_off = 0;   idx = tid - 131072; }
    else if (tid < 163840) { W = W_p2; N = 128; KT = 4; base = PK_P2;    k_off = 0;   idx = tid - 147456; }
    else                   { W = W_a;  N = 128; KT = 4; base = PK_WA;    k_off = 0;   idx = tid - 163840; }
    const int k0 = idx / N, n = idx - k0 * N;
    const int k = k0 + k_off;
    const int ntile = n >> 4, nl = n & 15;
    const int ktile = k >> 5, kg = (k >> 3) & 3, j = k & 7;
    const int lane = (kg << 4) | nl;
    dst[base + (((ntile * KT + ktile) * 64 + lane) << 3) + j] = f2bf(W[idx]);
}

// ================= MFMA GEMM helper: 16 rows x (NTW*16) cols, K = KT*32 =====
template<int KT, int NTW>
__device__ __forceinline__ void mfma_gemm(const unsigned short* sA, int lda,
                                          const unsigned short* __restrict__ wpk,
                                          int w, int l, f32x4* acc)
{
    const int mrow = l & 15, kg = l >> 4;
    #pragma unroll
    for (int nt = 0; nt < NTW; ++nt) {
        f32x4 a; a[0] = 0.f; a[1] = 0.f; a[2] = 0.f; a[3] = 0.f;
        const int ntile = w * NTW + nt;
        #pragma unroll
        for (int kt = 0; kt < KT; ++kt) {
            const short8v av = *(const short8v*)(sA + mrow * lda + kt * 32 + kg * 8);
            const short8v bv = *(const short8v*)(wpk + ((size_t)((ntile * KT + kt) * 64 + l) << 3));
            a = __builtin_amdgcn_mfma_f32_16x16x32_bf16(av, bv, a, 0, 0, 0);
        }
        acc[nt] = a;
    }
}

// ================= Kernel B v3: MFMA MLP + LSTM + heads (16 rows/block) =====
__global__ __launch_bounds__(256) void kb_lstm_mfma(
    const float* __restrict__ hx, const float* __restrict__ cx,
    const unsigned short* __restrict__ wpk,
    const float* __restrict__ b_p1, const float* __restrict__ b_p2,
    const float* __restrict__ b_ih, const float* __restrict__ b_hh,
    const float* __restrict__ b_a,
    const float* __restrict__ W_mx, const float* __restrict__ b_mx,
    const float* __restrict__ W_my, const float* __restrict__ b_my,
    const float* __restrict__ W_fi, const float* __restrict__ b_fi,
    const float* __restrict__ W_he, const float* __restrict__ b_he,
    const float* __restrict__ W_ra, const float* __restrict__ b_ra,
    const float* __restrict__ W_rb, const float* __restrict__ b_rb,
    float* out)
{
    const int t = threadIdx.x;
    const int l = t & 63;
    const int w = __builtin_amdgcn_readfirstlane(t >> 6);   // wave 0..3
    const int r0 = blockIdx.x * BB;
    const int mrow = l & 15, kg = l >> 4;

    __shared__ __align__(16) unsigned short s_a[BB][264];  // bf16 A: X|hx -> Y -> R|hx -> F
    __shared__ float s_r[BB][132];                          // reactive fp32
    __shared__ float s_g[BB][516];                          // gates fp32
    __shared__ float s_h[BB][132];                          // h fp32

    // ---- stage combined (bf16) + hx (bf16)
    for (int idx = t; idx < BB * 128; idx += 256) {
        const int r = idx >> 7, j = idx & 127;
        s_a[r][j]       = f2bf(out[(size_t)(r0 + r) * 268 + 12 + j]);
        s_a[r][128 + j] = f2bf(hx[(size_t)(r0 + r) * 128 + j]);
    }
    __syncthreads();

    f32x4 acc2[2];

    // ---- p1: Y = relu(X @ W_p1 + b_p1)   (wave owns 2 n-tiles)
    mfma_gemm<4, 2>(&s_a[0][0], 264, wpk + PK_P1, w, l, acc2);
    __syncthreads();
    #pragma unroll
    for (int nt = 0; nt < 2; ++nt) {
        const int col = (w * 2 + nt) * 16 + mrow;
        const float bb = b_p1[col];
        #pragma unroll
        for (int i = 0; i < 4; ++i)
            s_a[kg * 4 + i][col] = f2bf(fmaxf(acc2[nt][i] + bb, 0.0f));
    }
    __syncthreads();

    // ---- p2: R = relu(Y @ W_p2 + b_p2)
    mfma_gemm<4, 2>(&s_a[0][0], 264, wpk + PK_P2, w, l, acc2);
    __syncthreads();
    #pragma unroll
    for (int nt = 0; nt < 2; ++nt) {
        const int col = (w * 2 + nt) * 16 + mrow;
        const float bb = b_p2[col];
        #pragma unroll
        for (int i = 0; i < 4; ++i) {
            const float v = fmaxf(acc2[nt][i] + bb, 0.0f);
            s_r[kg * 4 + i][col] = v;
            s_a[kg * 4 + i][col] = f2bf(v);
        }
    }
    __syncthreads();

    // ---- gates: G = [R|hx] @ [W_ih;W_hh] + b   (K=256; wave owns 8 n-tiles)
    {
        f32x4 acc8[8];
        mfma_gemm<8, 8>(&s_a[0][0], 264, wpk + PK_GATES, w, l, acc8);
        #pragma unroll
        for (int nt = 0; nt < 8; ++nt) {
            const int col = (w * 8 + nt) * 16 + mrow;
            const float bb = b_ih[col] + b_hh[col];
            #pragma unroll
            for (int i = 0; i < 4; ++i)
                s_g[kg * 4 + i][col] = acc8[nt][i] + bb;
        }
    }
    __syncthreads();

    // ---- LSTM elementwise (i,f,g,o); features -> s_a bf16
    for (int idx = t; idx < BB * 128; idx += 256) {
        const int r = idx >> 7, j = idx & 127;
        const float ig = s_g[r][j];
        const float fg = s_g[r][j + 128];
        const float gg = s_g[r][j + 256];
        const float og = s_g[r][j + 384];
        const float c_old = cx[(size_t)(r0 + r) * 128 + j];
        const float c_new = sigf(fg) * c_old + sigf(ig) * tanhf(gg);
        const float h_new = sigf(og) * tanhf(c_new);
        out[(size_t)(r0 + r) * 268 + 12 + j]  = h_new;
        out[(size_t)(r0 + r) * 268 + 140 + j] = c_new;
        s_a[r][j] = f2bf(s_r[r][j] + h_new);     // features = reactive + hx_new
    }
    __syncthreads();

    // ---- W_a: H = relu(F @ W_a + b_a)
    mfma_gemm<4, 2>(&s_a[0][0], 264, wpk + PK_WA, w, l, acc2);
    #pragma unroll
    for (int nt = 0; nt < 2; ++nt) {
        const int col = (w * 2 + nt) * 16 + mrow;
        const float bb = b_a[col];
        #pragma unroll
        for (int i = 0; i < 4; ++i)
            s_h[kg * 4 + i][col] = fmaxf(acc2[nt][i] + bb, 0.0f);
    }
    __syncthreads();

    // ---- small heads: 12 scalar outputs per row
    if (t < BB * 12) {
        const int r = t / 12, ww = t % 12;
        const float* Wm; const float* bm; int nc, c, off;
        if (ww < 3)       { Wm = W_mx; bm = b_mx; nc = 3; c = ww;     off = ww; }
        else if (ww < 6)  { Wm = W_my; bm = b_my; nc = 3; c = ww - 3; off = ww; }
        else if (ww < 8)  { Wm = W_fi; bm = b_fi; nc = 2; c = ww - 6; off = ww; }
        else if (ww < 10) { Wm = W_he; bm = b_he; nc = 2; c = ww - 8; off = ww; }
        else if (ww == 10){ Wm = W_ra; bm = b_ra; nc = 1; c = 0;      off = 10; }
        else              { Wm = W_rb; bm = b_rb; nc = 1; c = 0;      off = 11; }
        float acc = bm[c];
        for (int i = 0; i < 128; ++i) acc = fmaf(s_h[r][i], Wm[i * nc + c], acc);
        if (ww >= 10) acc = fmaxf(acc, 0.0f) + log1pf(__expf(-fabsf(acc))) + 1.0f;
        out[(size_t)(r0 + r) * 268 + off] = acc;
    }
}

// ================= fallback Kernel B (fp32 gemv, 512 threads) ===============
__device__ __forceinline__ void gemv128_512(const float (*s_in)[128], float (*s_out)[128],
                                            const float* __restrict__ W,
                                            const float* __restrict__ bvec,
                                            int t, bool relu_)
{
    const int oo = t & 127;
    const int rb = (t >> 7) * 4;
    const float bv = bvec[oo];
    float acc[4];
    #pragma unroll
    for (int r = 0; r < 4; ++r) acc[r] = bv;
    #pragma unroll 4
    for (int i = 0; i < 128; ++i) {
        const float wt = W[i * 128 + oo];
        #pragma unroll
        for (int r = 0; r < 4; ++r) acc[r] = fmaf(s_in[rb + r][i], wt, acc[r]);
    }
    #pragma unroll
    for (int r = 0; r < 4; ++r) s_out[rb + r][oo] = relu_ ? fmaxf(acc[r], 0.0f) : acc[r];
}

__global__ __launch_bounds__(512) void kb_lstm_heads(
    const float* __restrict__ hx, const float* __restrict__ cx,
    const float* __restrict__ W_p1, const float* __restrict__ b_p1,
    const float* __restrict__ W_p2, const float* __restrict__ b_p2,
    const float* __restrict__ W_ih, const float* __restrict__ b_ih,
    const float* __restrict__ W_hh, const float* __restrict__ b_hh,
    const float* __restrict__ W_a,  const float* __restrict__ b_a,
    const float* __restrict__ W_mx, const float* __restrict__ b_mx,
    const float* __restrict__ W_my, const float* __restrict__ b_my,
    const float* __restrict__ W_fi, const float* __restrict__ b_fi,
    const float* __restrict__ W_he, const float* __restrict__ b_he,
    const float* __restrict__ W_ra, const float* __restrict__ b_ra,
    const float* __restrict__ W_rb, const float* __restrict__ b_rb,
    float* out)
{
    const int t = threadIdx.x;
    const int r0 = blockIdx.x * BB;

    __shared__ float s_x[BB][128];
    __shared__ float s_y[BB][128];
    __shared__ float s_hx[BB][128];
    __shared__ float s_g[BB][512];

    for (int idx = t; idx < BB * 128; idx += 512) {
        const int r = idx >> 7, j = idx & 127;
        s_x[r][j]  = out[(size_t)(r0 + r) * 268 + 12 + j];
        s_hx[r][j] = hx[(size_t)(r0 + r) * 128 + j];
    }
    __syncthreads();

    gemv128_512(s_x, s_y, W_p1, b_p1, t, true);
    __syncthreads();
    gemv128_512(s_y, s_x, W_p2, b_p2, t, true);
    __syncthreads();

    {
        float acc[16];
        const float bs = b_ih[t] + b_hh[t];
        #pragma unroll
        for (int r = 0; r < 16; ++r) acc[r] = bs;
        #pragma unroll 4
        for (int i = 0; i < 128; ++i) {
            const float w1 = W_ih[i * 512 + t];
            #pragma unroll
            for (int r = 0; r < 16; ++r) acc[r] = fmaf(s_x[r][i], w1, acc[r]);
        }
        #pragma unroll 4
        for (int i = 0; i < 128; ++i) {
            const float w1 = W_hh[i * 512 + t];
            #pragma unroll
            for (int r = 0; r < 16; ++r) acc[r] = fmaf(s_hx[r][i], w1, acc[r]);
        }
        #pragma unroll
        for (int r = 0; r < 16; ++r) s_g[r][t] = acc[r];
    }
    __syncthreads();

    for (int idx = t; idx < BB * 128; idx += 512) {
        const int r = idx >> 7, j = idx & 127;
        const float ig = s_g[r][j];
        const float fg = s_g[r][j + 128];
        const float gg = s_g[r][j + 256];
        const float og = s_g[r][j + 384];
        const float c_old = cx[(size_t)(r0 + r) * 128 + j];
        const float c_new = sigf(fg) * c_old + sigf(ig) * tanhf(gg);
        const float h_new = sigf(og) * tanhf(c_new);
        out[(size_t)(r0 + r) * 268 + 12 + j]  = h_new;
        out[(size_t)(r0 + r) * 268 + 140 + j] = c_new;
        s_y[r][j] = s_x[r][j] + h_new;
    }
    __syncthreads();

    gemv128_512(s_y, s_x, W_a, b_a, t, true);
    __syncthreads();

    if (t < BB * 12) {
        const int r = t / 12, ww = t % 12;
        const float* Wm; const float* bm; int nc, c, off;
        if (ww < 3)       { Wm = W_mx; bm = b_mx; nc = 3; c = ww;     off = ww; }
        else if (ww < 6)  { Wm = W_my; bm = b_my; nc = 3; c = ww - 3; off = ww; }
        else if (ww < 8)  { Wm = W_fi; bm = b_fi; nc = 2; c = ww - 6; off = ww; }
        else if (ww < 10) { Wm = W_he; bm = b_he; nc = 2; c = ww - 8; off = ww; }
        else if (ww == 10){ Wm = W_ra; bm = b_ra; nc = 1; c = 0;      off = 10; }
        else              { Wm = W_rb; bm = b_rb; nc = 1; c = 0;      off = 11; }
        float acc = bm[c];
        for (int i = 0; i < 128; ++i) acc = fmaf(s_x[r][i], Wm[i * nc + c], acc);
        if (ww >= 10) acc = fmaxf(acc, 0.0f) + log1pf(__expf(-fabsf(acc))) + 1.0f;
        out[(size_t)(r0 + r) * 268 + off] = acc;
    }
}

extern "C" void kernel_launch(void* const* d_in, const int* in_sizes, int n_in,
                              void* d_out, int out_size, void* d_ws, size_t ws_size,
                              hipStream_t stream) {
    (void)n_in; (void)out_size;
    const float* self_feat = (const float*)d_in[0];
    const float* entities  = (const float*)d_in[1];
    const void*  mask      = d_in[2];
    const float* hx  = (const float*)d_in[3];
    const float* cx  = (const float*)d_in[4];
    const float* W_se = (const float*)d_in[5],  *b_se = (const float*)d_in[6];
    const float* W_ee = (const float*)d_in[7],  *b_ee = (const float*)d_in[8];
    const float* W_q  = (const float*)d_in[9],  *b_q  = (const float*)d_in[10];
    const float* W_k  = (const float*)d_in[11], *b_k  = (const float*)d_in[12];
    const float* W_v  = (const float*)d_in[13], *b_v  = (const float*)d_in[14];
    const float* W_p1 = (const float*)d_in[15], *b_p1 = (const float*)d_in[16];
    const float* W_p2 = (const float*)d_in[17], *b_p2 = (const float*)d_in[18];
    const float* W_ih = (const float*)d_in[19], *b_ih = (const float*)d_in[20];
    const float* W_hh = (const float*)d_in[21], *b_hh = (const float*)d_in[22];
    const float* W_a  = (const float*)d_in[23], *b_a  = (const float*)d_in[24];
    const float* W_mx = (const float*)d_in[25], *b_mx = (const float*)d_in[26];
    const float* W_my = (const float*)d_in[27], *b_my = (const float*)d_in[28];
    const float* W_fi = (const float*)d_in[29], *b_fi = (const float*)d_in[30];
    const float* W_he = (const float*)d_in[31], *b_he = (const float*)d_in[32];
    const float* W_ra = (const float*)d_in[33], *b_ra = (const float*)d_in[34];
    const float* W_rb = (const float*)d_in[35], *b_rb = (const float*)d_in[36];
    float* out = (float*)d_out;

    const int B = in_sizes[0] / 24;   // 8192
    const bool use_mfma = ws_size >= (size_t)(PK_TOTAL * 2);

    if (use_mfma) {
        pack_weights<<<PK_TOTAL / 256, 256, 0, stream>>>(
            W_ih, W_hh, W_p1, W_p2, W_a, (unsigned short*)d_ws);
    }

    ka_attention_v5<<<B / 4, 256, 0, stream>>>(self_feat, entities, mask,
        W_se, b_se, W_ee, b_ee, W_q, b_q, W_k, b_k, W_v, b_v, out);

    if (use_mfma) {
        kb_lstm_mfma<<<B / BB, 256, 0, stream>>>(hx, cx, (const unsigned short*)d_ws,
            b_p1, b_p2, b_ih, b_hh, b_a,
            W_mx, b_mx, W_my, b_my, W_fi, b_fi, W_he, b_he, W_ra, b_ra, W_rb, b_rb, out);
    } else {
        kb_lstm_heads<<<B / BB, 512, 0, stream>>>(hx, cx,
            W_p1, b_p1, W_p2, b_p2, W_ih, b_ih, W_hh, b_hh, W_a, b_a,
            W_mx, b_mx, W_my, b_my, W_fi, b_fi, W_he, b_he, W_ra, b_ra, W_rb, b_rb, out);
    }
}